// Round 11
// baseline (209.753 us; speedup 1.0000x reference)
//
#include <hip/hip_runtime.h>

#define N_NODES 100000
#define F_IN 128
#define F_HID 32
#define BN 512                  // nodes per bucket (pow2)
#define NBUCK 196               // ceil(100000/512)
#define NBLK 128                // edge partition chunks (64 entries/bucket avg -> 256B runs)
#define G1_BLOCK 256
#define G1_NODES 64             // nodes per gemm1 block

// ---------------- phase A: bucket partition of edges (no global atomics) ----------------

__global__ __launch_bounds__(256) void part_count(const int* __restrict__ src,
                                                  const int* __restrict__ dst, int E,
                                                  unsigned* __restrict__ cntD,
                                                  unsigned* __restrict__ cntS) {
    __shared__ unsigned cd[NBUCK], cs[NBUCK];
    for (int i = threadIdx.x; i < NBUCK; i += 256) { cd[i] = 0; cs[i] = 0; }
    __syncthreads();
    int chunk = (E + NBLK - 1) / NBLK;
    int e0 = blockIdx.x * chunk, e1 = min(E, e0 + chunk);
    for (int e = e0 + threadIdx.x; e < e1; e += 256) {
        atomicAdd(&cd[((unsigned)dst[e]) >> 9], 1u);   // LDS atomic
        atomicAdd(&cs[((unsigned)src[e]) >> 9], 1u);
    }
    __syncthreads();
    unsigned* od = cntD + (size_t)blockIdx.x * NBUCK;
    unsigned* os = cntS + (size_t)blockIdx.x * NBUCK;
    for (int i = threadIdx.x; i < NBUCK; i += 256) { od[i] = cd[i]; os[i] = cs[i]; }
}

// per-bucket exclusive scan over blocks (in place); totals[k] = bucket size
__global__ __launch_bounds__(NBLK) void col_scan(unsigned* __restrict__ cnt,
                                                 unsigned* __restrict__ totals) {
    __shared__ unsigned buf[2][NBLK];
    int k = blockIdx.x, t = threadIdx.x;
    unsigned v = cnt[(size_t)t * NBUCK + k];
    buf[0][t] = v;
    __syncthreads();
    int cur = 0;
    for (int off = 1; off < NBLK; off <<= 1) {
        unsigned x = buf[cur][t];
        if (t >= off) x += buf[cur][t - off];
        buf[cur ^ 1][t] = x;
        cur ^= 1;
        __syncthreads();
    }
    cnt[(size_t)t * NBUCK + k] = buf[cur][t] - v;  // exclusive over blocks
    if (t == NBLK - 1) totals[k] = buf[cur][NBLK - 1];
}

// exclusive scan of bucket totals -> start[0..NBUCK] (start[NBUCK] = E)
__global__ __launch_bounds__(1024) void total_scan(const unsigned* __restrict__ totals,
                                                   unsigned* __restrict__ start) {
    __shared__ unsigned buf[2][1024];
    int t = threadIdx.x;
    buf[0][t] = (t < NBUCK) ? totals[t] : 0;
    __syncthreads();
    int cur = 0;
    for (int off = 1; off < 1024; off <<= 1) {
        unsigned x = buf[cur][t];
        if (t >= off) x += buf[cur][t - off];
        buf[cur ^ 1][t] = x;
        cur ^= 1;
        __syncthreads();
    }
    if (t < NBUCK) start[t + 1] = buf[cur][t];
    if (t == 0) start[0] = 0;
}

// scatter edges into bucket-partitioned layout; slots disjoint by construction
__global__ __launch_bounds__(256) void part_scatter(const int* __restrict__ src,
                                                    const int* __restrict__ dst, int E,
                                                    const unsigned* __restrict__ cntD,
                                                    const unsigned* __restrict__ cntS,
                                                    const unsigned* __restrict__ startD,
                                                    const unsigned* __restrict__ startS,
                                                    unsigned* __restrict__ pairD,
                                                    unsigned* __restrict__ valS) {
    __shared__ unsigned curD[NBUCK], curS[NBUCK];
    for (int i = threadIdx.x; i < NBUCK; i += 256) { curD[i] = 0; curS[i] = 0; }
    __syncthreads();
    int chunk = (E + NBLK - 1) / NBLK;
    int e0 = blockIdx.x * chunk, e1 = min(E, e0 + chunk);
    const unsigned* bd = cntD + (size_t)blockIdx.x * NBUCK;
    const unsigned* bs = cntS + (size_t)blockIdx.x * NBUCK;
    for (int e = e0 + threadIdx.x; e < e1; e += 256) {
        unsigned s = (unsigned)src[e], d = (unsigned)dst[e];
        unsigned kd = d >> 9, ks = s >> 9;
        unsigned rd = atomicAdd(&curD[kd], 1u);                 // LDS rank
        pairD[startD[kd] + bd[kd] + rd] = s | ((d & 511u) << 17);
        unsigned rs = atomicAdd(&curS[ks], 1u);
        valS[startS[ks] + bs[ks] + rs] = s & 511u;
    }
}

// ---------------- phase B: per-bucket counting sort -> full CSR (no global atomics) ----------
// BN=512 bins, 256 threads: each thread owns bins t and t+256.

__global__ __launch_bounds__(256) void bucket_sort(const unsigned* __restrict__ pairD,
                                                   const unsigned* __restrict__ startD,
                                                   int* __restrict__ col, int* __restrict__ row_ptr,
                                                   int* __restrict__ deg_arr,
                                                   float* __restrict__ norm_in, int n) {
    __shared__ unsigned cnt[BN];
    __shared__ unsigned base[BN];
    __shared__ unsigned sbuf[2][BN];
    int t = threadIdx.x;
    cnt[t] = 0; cnt[t + 256] = 0;
    __syncthreads();
    int k = blockIdx.x;
    unsigned a0 = startD[k], a1 = startD[k + 1];
    for (unsigned i = a0 + t; i < a1; i += 256)
        atomicAdd(&cnt[(pairD[i] >> 17) & (BN - 1)], 1u);
    __syncthreads();
    unsigned v0 = cnt[t], v1 = cnt[t + 256];
    sbuf[0][t] = v0; sbuf[0][t + 256] = v1;
    __syncthreads();
    int cur = 0;
    for (int off = 1; off < BN; off <<= 1) {
        unsigned x0 = sbuf[cur][t];
        if (t >= off) x0 += sbuf[cur][t - off];
        unsigned x1 = sbuf[cur][t + 256] + sbuf[cur][t + 256 - off];  // t+256 >= off always
        sbuf[cur ^ 1][t] = x0;
        sbuf[cur ^ 1][t + 256] = x1;
        cur ^= 1;
        __syncthreads();
    }
    {
        base[t] = a0 + sbuf[cur][t] - v0;
        base[t + 256] = a0 + sbuf[cur][t + 256] - v1;
        int node0 = k * BN + t, node1 = k * BN + t + 256;
        if (node0 < n) {
            row_ptr[node0] = (int)base[t];
            deg_arr[node0] = (int)v0;
            norm_in[node0] = rsqrtf((float)(v0 > 1u ? v0 : 1u));
        }
        if (node1 < n) {
            row_ptr[node1] = (int)base[t + 256];
            deg_arr[node1] = (int)v1;
            norm_in[node1] = rsqrtf((float)(v1 > 1u ? v1 : 1u));
        }
        cnt[t] = 0; cnt[t + 256] = 0;
    }
    __syncthreads();
    for (unsigned i = a0 + t; i < a1; i += 256) {
        unsigned pv = pairD[i];
        unsigned l = (pv >> 17) & (BN - 1);
        unsigned r = atomicAdd(&cnt[l], 1u);   // LDS rank
        col[base[l] + r] = (int)(pv & 0x1FFFFu);
    }
}

// src-side degree -> norm_out
__global__ __launch_bounds__(256) void bucket_norms_src(const unsigned* __restrict__ valS,
                                                        const unsigned* __restrict__ startS,
                                                        float* __restrict__ norm_out, int n) {
    __shared__ unsigned cnt[BN];
    int t = threadIdx.x;
    cnt[t] = 0; cnt[t + 256] = 0;
    __syncthreads();
    int k = blockIdx.x;
    unsigned a0 = startS[k], a1 = startS[k + 1];
    for (unsigned i = a0 + t; i < a1; i += 256)
        atomicAdd(&cnt[valS[i]], 1u);
    __syncthreads();
#pragma unroll
    for (int h = 0; h < 2; ++h) {
        int l = t + h * 256;
        int node = k * BN + l;
        if (node < n) {
            unsigned c = cnt[l];
            norm_out[node] = rsqrtf((float)(c > 1u ? c : 1u));
        }
    }
}

// ---------------- layer-1 projection: Xs-only LDS (33.8 KB), W via global/L1 ----------------
// 256 threads / 64 nodes: group g (0..31) owns rows g and g+32; padded rows (33 float4)
// give bank 4g+4k4 -> 8 groups x 4 banks tile all 32 banks; same-g lanes broadcast.

__device__ __forceinline__ void fma4(float4& a, float s, float4 w) {
    a.x += s * w.x; a.y += s * w.y; a.z += s * w.z; a.w += s * w.w;
}

__global__ __launch_bounds__(G1_BLOCK) void gemm1_kernel(const float* __restrict__ x,
                                                         const float* __restrict__ W,
                                                         const float* __restrict__ norm_out,
                                                         float* __restrict__ h, int n) {
    __shared__ float4 Xs[G1_NODES * 33];  // 33792 B
    int nb = blockIdx.x * G1_NODES;
    int nrows = n - nb; if (nrows > G1_NODES) nrows = G1_NODES;
    const float4* x4 = reinterpret_cast<const float4*>(x + (size_t)nb * F_IN);
    for (int i = threadIdx.x; i < nrows * 32; i += G1_BLOCK)
        Xs[(i >> 5) * 33 + (i & 31)] = x4[i];
    __syncthreads();
    const float4* W4 = reinterpret_cast<const float4*>(W);
    int q = threadIdx.x & 7;      // output quad: j = 4q..4q+3
    int g = threadIdx.x >> 3;     // group 0..31; nodes g, g+32
    float4 acc0 = make_float4(0.f, 0.f, 0.f, 0.f);
    float4 acc1 = acc0;
#pragma unroll 4
    for (int k4 = 0; k4 < 32; ++k4) {
        float4 xv0 = Xs[(g + 0) * 33 + k4];
        float4 xv1 = Xs[(g + 32) * 33 + k4];
        float4 w0 = W4[(k4 * 4 + 0) * 8 + q];
        float4 w1 = W4[(k4 * 4 + 1) * 8 + q];
        float4 w2 = W4[(k4 * 4 + 2) * 8 + q];
        float4 w3 = W4[(k4 * 4 + 3) * 8 + q];
        fma4(acc0, xv0.x, w0); fma4(acc0, xv0.y, w1); fma4(acc0, xv0.z, w2); fma4(acc0, xv0.w, w3);
        fma4(acc1, xv1.x, w0); fma4(acc1, xv1.y, w1); fma4(acc1, xv1.z, w2); fma4(acc1, xv1.w, w3);
    }
    float4* h4 = reinterpret_cast<float4*>(h);
    float4 accs[2] = {acc0, acc1};
#pragma unroll
    for (int i = 0; i < 2; ++i) {
        int node = nb + g + 32 * i;
        if (node < n) {
            float no = norm_out[node];
            float4 o = accs[i];
            o.x *= no; o.y *= no; o.z *= no; o.w *= no;
            h4[(size_t)node * 8 + q] = o;
        }
    }
}

// ---------------- gather aggregation: 8 lanes/node, float4/lane, 8-edge unroll --------------

__device__ __forceinline__ float4 shfl4_8(float4 v, int sl) {
    float4 r;
    r.x = __shfl(v.x, sl, 8);
    r.y = __shfl(v.y, sl, 8);
    r.z = __shfl(v.z, sl, 8);
    r.w = __shfl(v.w, sl, 8);
    return r;
}

// layer 1: agg + norm_in + b1 + relu, GEMM2 (8-lane shfl), prescale norm_out -> h2s
__global__ __launch_bounds__(256) void agg1_kernel(const float* __restrict__ h1s,
                                                   const int* __restrict__ row_ptr,
                                                   const int* __restrict__ deg_arr,
                                                   const int* __restrict__ col,
                                                   const float* __restrict__ norm_in,
                                                   const float* __restrict__ norm_out,
                                                   const float* __restrict__ b1,
                                                   const float* __restrict__ W2,
                                                   float* __restrict__ h2s, int n) {
    __shared__ float W2l[F_HID * F_HID];  // row k holds W2[k][0..31]
    for (int i = threadIdx.x; i < F_HID * F_HID; i += 256) W2l[i] = W2[i];
    __syncthreads();
    const float4* h4 = reinterpret_cast<const float4*>(h1s);
    const float4* W24 = reinterpret_cast<const float4*>(W2l);
    int q = threadIdx.x & 7;                 // lane in 8-lane group
    int node = blockIdx.x * 32 + (threadIdx.x >> 3);
    if (node >= n) return;
    int start = row_ptr[node];
    int deg = deg_arr[node];
    float4 acc = make_float4(0.f, 0.f, 0.f, 0.f);
    int jj = 0;
    for (; jj + 8 <= deg; jj += 8) {
        int c = col[start + jj + q];         // 8 lanes: one coalesced 32B load
#pragma unroll
        for (int m = 0; m < 8; ++m) {
            int s = __shfl(c, m, 8);
            float4 v = h4[(size_t)s * 8 + q];
            acc.x += v.x; acc.y += v.y; acc.z += v.z; acc.w += v.w;
        }
    }
    int rem = deg - jj;
    if (rem > 0) {
        int c = col[start + jj + (q < rem ? q : 0)];
        for (int m = 0; m < rem; ++m) {
            int s = __shfl(c, m, 8);
            float4 v = h4[(size_t)s * 8 + q];
            acc.x += v.x; acc.y += v.y; acc.z += v.z; acc.w += v.w;
        }
    }
    float ni = norm_in[node];
    const float4 b14 = reinterpret_cast<const float4*>(b1)[q];
    float4 t;
    t.x = fmaxf(acc.x * ni + b14.x, 0.f);
    t.y = fmaxf(acc.y * ni + b14.y, 0.f);
    t.z = fmaxf(acc.z * ni + b14.z, 0.f);
    t.w = fmaxf(acc.w * ni + b14.w, 0.f);
    // GEMM2: o[f] = sum_k t[k] * W2[k][f]; t distributed 4-per-lane over 8 lanes
    float4 o = make_float4(0.f, 0.f, 0.f, 0.f);
#pragma unroll
    for (int sl = 0; sl < 8; ++sl) {
        float4 tt = shfl4_8(t, sl);
        int kb = sl * 4;
        float4 w0 = W24[(kb + 0) * 8 + q];
        float4 w1 = W24[(kb + 1) * 8 + q];
        float4 w2 = W24[(kb + 2) * 8 + q];
        float4 w3 = W24[(kb + 3) * 8 + q];
        o.x += tt.x * w0.x + tt.y * w1.x + tt.z * w2.x + tt.w * w3.x;
        o.y += tt.x * w0.y + tt.y * w1.y + tt.z * w2.y + tt.w * w3.y;
        o.z += tt.x * w0.z + tt.y * w1.z + tt.z * w2.z + tt.w * w3.z;
        o.w += tt.x * w0.w + tt.y * w1.w + tt.z * w2.w + tt.w * w3.w;
    }
    float no = norm_out[node];
    o.x *= no; o.y *= no; o.z *= no; o.w *= no;
    reinterpret_cast<float4*>(h2s)[(size_t)node * 8 + q] = o;
}

// layer 2: agg + norm_in + b2 -> out
__global__ __launch_bounds__(256) void agg2_kernel(const float* __restrict__ h2s,
                                                   const int* __restrict__ row_ptr,
                                                   const int* __restrict__ deg_arr,
                                                   const int* __restrict__ col,
                                                   const float* __restrict__ norm_in,
                                                   const float* __restrict__ b2,
                                                   float* __restrict__ out, int n) {
    const float4* h4 = reinterpret_cast<const float4*>(h2s);
    int q = threadIdx.x & 7;
    int node = blockIdx.x * 32 + (threadIdx.x >> 3);
    if (node >= n) return;
    int start = row_ptr[node];
    int deg = deg_arr[node];
    float4 acc = make_float4(0.f, 0.f, 0.f, 0.f);
    int jj = 0;
    for (; jj + 8 <= deg; jj += 8) {
        int c = col[start + jj + q];
#pragma unroll
        for (int m = 0; m < 8; ++m) {
            int s = __shfl(c, m, 8);
            float4 v = h4[(size_t)s * 8 + q];
            acc.x += v.x; acc.y += v.y; acc.z += v.z; acc.w += v.w;
        }
    }
    int rem = deg - jj;
    if (rem > 0) {
        int c = col[start + jj + (q < rem ? q : 0)];
        for (int m = 0; m < rem; ++m) {
            int s = __shfl(c, m, 8);
            float4 v = h4[(size_t)s * 8 + q];
            acc.x += v.x; acc.y += v.y; acc.z += v.z; acc.w += v.w;
        }
    }
    float ni = norm_in[node];
    const float4 b24 = reinterpret_cast<const float4*>(b2)[q];
    float4 o;
    o.x = acc.x * ni + b24.x;
    o.y = acc.y * ni + b24.y;
    o.z = acc.z * ni + b24.z;
    o.w = acc.w * ni + b24.w;
    reinterpret_cast<float4*>(out)[(size_t)node * 8 + q] = o;
}

// ---------------- launch ----------------

static inline size_t align256(size_t x) { return (x + 255) & ~(size_t)255; }

extern "C" void kernel_launch(void* const* d_in, const int* in_sizes, int n_in,
                              void* d_out, int out_size, void* d_ws, size_t ws_size,
                              hipStream_t stream) {
    const float* features = (const float*)d_in[0];
    const float* W1 = (const float*)d_in[1];
    const float* b1 = (const float*)d_in[2];
    const float* W2 = (const float*)d_in[3];
    const float* b2 = (const float*)d_in[4];
    const int* src = (const int*)d_in[5];
    const int* dst = (const int*)d_in[6];
    const int E = in_sizes[5];
    const int n = N_NODES;
    float* out = (float*)d_out;

    char* ws = (char*)d_ws;
    size_t off = 0;
    float* norm_out = (float*)(ws + off); off += align256((size_t)n * 4);
    float* norm_in = (float*)(ws + off);  off += align256((size_t)n * 4);
    int* row_ptr = (int*)(ws + off);      off += align256((size_t)n * 4);
    int* deg_arr = (int*)(ws + off);      off += align256((size_t)n * 4);
    unsigned* startD = (unsigned*)(ws + off); off += align256((NBUCK + 1) * 4);
    unsigned* startS = (unsigned*)(ws + off); off += align256((NBUCK + 1) * 4);
    unsigned* totD = (unsigned*)(ws + off);   off += align256(NBUCK * 4);
    unsigned* totS = (unsigned*)(ws + off);   off += align256(NBUCK * 4);
    int* col = (int*)(ws + off);              off += align256((size_t)E * 4);  // 6.4 MB

    // region X: pairD+valS (live: part_scatter -> bucket kernels) then h2s (live: agg1 -> agg2)
    size_t regX = off;
    unsigned* pairD = (unsigned*)(ws + regX);                        // 6.4 MB
    unsigned* valS = (unsigned*)(ws + regX + (size_t)E * 4);         // 6.4 MB
    float* h2s = (float*)(ws + regX);                                // 12.8 MB
    off += align256((size_t)2 * E * 4);
    // region Y: cntD+cntS (live: part_count -> part_scatter) then h1s (live: gemm1 -> agg1)
    size_t regY = off;
    unsigned* cntD = (unsigned*)(ws + regY);                         // 100 KB
    unsigned* cntS = (unsigned*)(ws + regY + (size_t)NBLK * NBUCK * 4);
    float* h1s = (float*)(ws + regY);                                // 12.8 MB

    // phase A: partition edges by dst-bucket (pairs) and src-bucket (locals)
    part_count<<<NBLK, 256, 0, stream>>>(src, dst, E, cntD, cntS);
    col_scan<<<NBUCK, NBLK, 0, stream>>>(cntD, totD);
    col_scan<<<NBUCK, NBLK, 0, stream>>>(cntS, totS);
    total_scan<<<1, 1024, 0, stream>>>(totD, startD);
    total_scan<<<1, 1024, 0, stream>>>(totS, startS);
    part_scatter<<<NBLK, 256, 0, stream>>>(src, dst, E, cntD, cntS, startD, startS, pairD, valS);

    // phase B: per-bucket counting sort -> CSR (+ norm_in), src norms
    bucket_sort<<<NBUCK, 256, 0, stream>>>(pairD, startD, col, row_ptr, deg_arr, norm_in, n);
    bucket_norms_src<<<NBUCK, 256, 0, stream>>>(valS, startS, norm_out, n);

    // layer 1 projection (+ norm_out prescale)
    gemm1_kernel<<<(n + G1_NODES - 1) / G1_NODES, G1_BLOCK, 0, stream>>>(features, W1, norm_out,
                                                                         h1s, n);

    // gather aggregation (8 lanes/node, float4), fused epilogues
    agg1_kernel<<<(n + 31) / 32, 256, 0, stream>>>(h1s, row_ptr, deg_arr, col, norm_in,
                                                   norm_out, b1, W2, h2s, n);
    agg2_kernel<<<(n + 31) / 32, 256, 0, stream>>>(h2s, row_ptr, deg_arr, col, norm_in, b2, out, n);
}

// Round 12
// 175.130 us; speedup vs baseline: 1.1977x; 1.1977x over previous
//
#include <hip/hip_runtime.h>

#define N_NODES 100000
#define F_IN 128
#define F_HID 32
#define BN 512                  // nodes per bucket (pow2)
#define NBUCK 196               // ceil(100000/512)
#define NBLK 128                // edge partition chunks (64 entries/bucket avg -> 256B runs)
#define PART_THREADS 1024
#define G1_BLOCK 256
#define G1_NODES 64             // nodes per gemm1 block

// ---------------- phase A: bucket partition of edges (no global atomics) ----------------

__global__ __launch_bounds__(PART_THREADS) void part_count(const int* __restrict__ src,
                                                           const int* __restrict__ dst, int E,
                                                           unsigned* __restrict__ cntD,
                                                           unsigned* __restrict__ cntS) {
    __shared__ unsigned cd[NBUCK], cs[NBUCK];
    for (int i = threadIdx.x; i < NBUCK; i += PART_THREADS) { cd[i] = 0; cs[i] = 0; }
    __syncthreads();
    int chunk = (E + NBLK - 1) / NBLK;
    int e0 = blockIdx.x * chunk, e1 = min(E, e0 + chunk);
    for (int e = e0 + threadIdx.x; e < e1; e += PART_THREADS) {
        atomicAdd(&cd[((unsigned)dst[e]) >> 9], 1u);   // LDS atomic
        atomicAdd(&cs[((unsigned)src[e]) >> 9], 1u);
    }
    __syncthreads();
    unsigned* od = cntD + (size_t)blockIdx.x * NBUCK;
    unsigned* os = cntS + (size_t)blockIdx.x * NBUCK;
    for (int i = threadIdx.x; i < NBUCK; i += PART_THREADS) { od[i] = cd[i]; os[i] = cs[i]; }
}

// per-bucket exclusive scan over blocks (in place); totals[k] = bucket size
__global__ __launch_bounds__(NBLK) void col_scan(unsigned* __restrict__ cnt,
                                                 unsigned* __restrict__ totals) {
    __shared__ unsigned buf[2][NBLK];
    int k = blockIdx.x, t = threadIdx.x;
    unsigned v = cnt[(size_t)t * NBUCK + k];
    buf[0][t] = v;
    __syncthreads();
    int cur = 0;
    for (int off = 1; off < NBLK; off <<= 1) {
        unsigned x = buf[cur][t];
        if (t >= off) x += buf[cur][t - off];
        buf[cur ^ 1][t] = x;
        cur ^= 1;
        __syncthreads();
    }
    cnt[(size_t)t * NBUCK + k] = buf[cur][t] - v;  // exclusive over blocks
    if (t == NBLK - 1) totals[k] = buf[cur][NBLK - 1];
}

// exclusive scan of bucket totals -> start[0..NBUCK] (start[NBUCK] = E)
__global__ __launch_bounds__(1024) void total_scan(const unsigned* __restrict__ totals,
                                                   unsigned* __restrict__ start) {
    __shared__ unsigned buf[2][1024];
    int t = threadIdx.x;
    buf[0][t] = (t < NBUCK) ? totals[t] : 0;
    __syncthreads();
    int cur = 0;
    for (int off = 1; off < 1024; off <<= 1) {
        unsigned x = buf[cur][t];
        if (t >= off) x += buf[cur][t - off];
        buf[cur ^ 1][t] = x;
        cur ^= 1;
        __syncthreads();
    }
    if (t < NBUCK) start[t + 1] = buf[cur][t];
    if (t == 0) start[0] = 0;
}

// scatter edges into bucket-partitioned layout; slots disjoint by construction
__global__ __launch_bounds__(PART_THREADS) void part_scatter(const int* __restrict__ src,
                                                             const int* __restrict__ dst, int E,
                                                             const unsigned* __restrict__ cntD,
                                                             const unsigned* __restrict__ cntS,
                                                             const unsigned* __restrict__ startD,
                                                             const unsigned* __restrict__ startS,
                                                             unsigned* __restrict__ pairD,
                                                             unsigned* __restrict__ valS) {
    __shared__ unsigned curD[NBUCK], curS[NBUCK];
    for (int i = threadIdx.x; i < NBUCK; i += PART_THREADS) { curD[i] = 0; curS[i] = 0; }
    __syncthreads();
    int chunk = (E + NBLK - 1) / NBLK;
    int e0 = blockIdx.x * chunk, e1 = min(E, e0 + chunk);
    const unsigned* bd = cntD + (size_t)blockIdx.x * NBUCK;
    const unsigned* bs = cntS + (size_t)blockIdx.x * NBUCK;
    for (int e = e0 + threadIdx.x; e < e1; e += PART_THREADS) {
        unsigned s = (unsigned)src[e], d = (unsigned)dst[e];
        unsigned kd = d >> 9, ks = s >> 9;
        unsigned rd = atomicAdd(&curD[kd], 1u);                 // LDS rank
        pairD[startD[kd] + bd[kd] + rd] = s | ((d & 511u) << 17);
        unsigned rs = atomicAdd(&curS[ks], 1u);
        valS[startS[ks] + bs[ks] + rs] = s & 511u;
    }
}

// ---------------- phase B: per-bucket counting sort -> full CSR (no global atomics) ----------
// BN=512 bins, 256 threads: each thread owns bins t and t+256.

__global__ __launch_bounds__(256) void bucket_sort(const unsigned* __restrict__ pairD,
                                                   const unsigned* __restrict__ startD,
                                                   int* __restrict__ col, int* __restrict__ row_ptr,
                                                   int* __restrict__ deg_arr,
                                                   float* __restrict__ norm_in, int n) {
    __shared__ unsigned cnt[BN];
    __shared__ unsigned base[BN];
    __shared__ unsigned sbuf[2][BN];
    int t = threadIdx.x;
    cnt[t] = 0; cnt[t + 256] = 0;
    __syncthreads();
    int k = blockIdx.x;
    unsigned a0 = startD[k], a1 = startD[k + 1];
    for (unsigned i = a0 + t; i < a1; i += 256)
        atomicAdd(&cnt[(pairD[i] >> 17) & (BN - 1)], 1u);
    __syncthreads();
    unsigned v0 = cnt[t], v1 = cnt[t + 256];
    sbuf[0][t] = v0; sbuf[0][t + 256] = v1;
    __syncthreads();
    int cur = 0;
    for (int off = 1; off < BN; off <<= 1) {
        unsigned x0 = sbuf[cur][t];
        if (t >= off) x0 += sbuf[cur][t - off];
        unsigned x1 = sbuf[cur][t + 256] + sbuf[cur][t + 256 - off];  // t+256 >= off always
        sbuf[cur ^ 1][t] = x0;
        sbuf[cur ^ 1][t + 256] = x1;
        cur ^= 1;
        __syncthreads();
    }
    {
        base[t] = a0 + sbuf[cur][t] - v0;
        base[t + 256] = a0 + sbuf[cur][t + 256] - v1;
        int node0 = k * BN + t, node1 = k * BN + t + 256;
        if (node0 < n) {
            row_ptr[node0] = (int)base[t];
            deg_arr[node0] = (int)v0;
            norm_in[node0] = rsqrtf((float)(v0 > 1u ? v0 : 1u));
        }
        if (node1 < n) {
            row_ptr[node1] = (int)base[t + 256];
            deg_arr[node1] = (int)v1;
            norm_in[node1] = rsqrtf((float)(v1 > 1u ? v1 : 1u));
        }
        cnt[t] = 0; cnt[t + 256] = 0;
    }
    __syncthreads();
    for (unsigned i = a0 + t; i < a1; i += 256) {
        unsigned pv = pairD[i];
        unsigned l = (pv >> 17) & (BN - 1);
        unsigned r = atomicAdd(&cnt[l], 1u);   // LDS rank
        col[base[l] + r] = (int)(pv & 0x1FFFFu);
    }
}

// src-side degree -> norm_out
__global__ __launch_bounds__(256) void bucket_norms_src(const unsigned* __restrict__ valS,
                                                        const unsigned* __restrict__ startS,
                                                        float* __restrict__ norm_out, int n) {
    __shared__ unsigned cnt[BN];
    int t = threadIdx.x;
    cnt[t] = 0; cnt[t + 256] = 0;
    __syncthreads();
    int k = blockIdx.x;
    unsigned a0 = startS[k], a1 = startS[k + 1];
    for (unsigned i = a0 + t; i < a1; i += 256)
        atomicAdd(&cnt[valS[i]], 1u);
    __syncthreads();
#pragma unroll
    for (int h = 0; h < 2; ++h) {
        int l = t + h * 256;
        int node = k * BN + l;
        if (node < n) {
            unsigned c = cnt[l];
            norm_out[node] = rsqrtf((float)(c > 1u ? c : 1u));
        }
    }
}

// ---------------- layer-1 projection: W + padded Xs both in LDS (49.9 KB) ----------------
// 256 threads / 64 nodes: group g (0..31) owns rows g, g+32. X banks: (4g+4k4)%32 tiles
// all 32 banks across the wave's 8 groups; W banks: 4q spans 32 banks, groups broadcast.

__device__ __forceinline__ void fma4(float4& a, float s, float4 w) {
    a.x += s * w.x; a.y += s * w.y; a.z += s * w.z; a.w += s * w.w;
}

__global__ __launch_bounds__(G1_BLOCK) void gemm1_kernel(const float* __restrict__ x,
                                                         const float* __restrict__ W,
                                                         const float* __restrict__ norm_out,
                                                         float* __restrict__ h, int n) {
    __shared__ float4 Xs[G1_NODES * 33];  // 33792 B, padded rows
    __shared__ float4 Ws[F_IN * 8];       // 16384 B
    const float4* W4 = reinterpret_cast<const float4*>(W);
    for (int i = threadIdx.x; i < F_IN * 8; i += G1_BLOCK) Ws[i] = W4[i];
    int nb = blockIdx.x * G1_NODES;
    int nrows = n - nb; if (nrows > G1_NODES) nrows = G1_NODES;
    const float4* x4 = reinterpret_cast<const float4*>(x + (size_t)nb * F_IN);
    for (int i = threadIdx.x; i < nrows * 32; i += G1_BLOCK)
        Xs[(i >> 5) * 33 + (i & 31)] = x4[i];
    __syncthreads();
    int q = threadIdx.x & 7;      // output quad: j = 4q..4q+3
    int g = threadIdx.x >> 3;     // group 0..31; nodes g, g+32
    float4 acc0 = make_float4(0.f, 0.f, 0.f, 0.f);
    float4 acc1 = acc0;
#pragma unroll 4
    for (int k4 = 0; k4 < 32; ++k4) {
        float4 xv0 = Xs[(g + 0) * 33 + k4];
        float4 xv1 = Xs[(g + 32) * 33 + k4];
        float4 w0 = Ws[(k4 * 4 + 0) * 8 + q];
        float4 w1 = Ws[(k4 * 4 + 1) * 8 + q];
        float4 w2 = Ws[(k4 * 4 + 2) * 8 + q];
        float4 w3 = Ws[(k4 * 4 + 3) * 8 + q];
        fma4(acc0, xv0.x, w0); fma4(acc0, xv0.y, w1); fma4(acc0, xv0.z, w2); fma4(acc0, xv0.w, w3);
        fma4(acc1, xv1.x, w0); fma4(acc1, xv1.y, w1); fma4(acc1, xv1.z, w2); fma4(acc1, xv1.w, w3);
    }
    float4* h4 = reinterpret_cast<float4*>(h);
    float4 accs[2] = {acc0, acc1};
#pragma unroll
    for (int i = 0; i < 2; ++i) {
        int node = nb + g + 32 * i;
        if (node < n) {
            float no = norm_out[node];
            float4 o = accs[i];
            o.x *= no; o.y *= no; o.z *= no; o.w *= no;
            h4[(size_t)node * 8 + q] = o;
        }
    }
}

// ---------------- gather aggregation: 8 lanes/node, float4/lane, 8-edge unroll --------------

__device__ __forceinline__ float4 shfl4_8(float4 v, int sl) {
    float4 r;
    r.x = __shfl(v.x, sl, 8);
    r.y = __shfl(v.y, sl, 8);
    r.z = __shfl(v.z, sl, 8);
    r.w = __shfl(v.w, sl, 8);
    return r;
}

// layer 1: agg + norm_in + b1 + relu, GEMM2 (8-lane shfl), prescale norm_out -> h2s
__global__ __launch_bounds__(256) void agg1_kernel(const float* __restrict__ h1s,
                                                   const int* __restrict__ row_ptr,
                                                   const int* __restrict__ deg_arr,
                                                   const int* __restrict__ col,
                                                   const float* __restrict__ norm_in,
                                                   const float* __restrict__ norm_out,
                                                   const float* __restrict__ b1,
                                                   const float* __restrict__ W2,
                                                   float* __restrict__ h2s, int n) {
    __shared__ float W2l[F_HID * F_HID];  // row k holds W2[k][0..31]
    for (int i = threadIdx.x; i < F_HID * F_HID; i += 256) W2l[i] = W2[i];
    __syncthreads();
    const float4* h4 = reinterpret_cast<const float4*>(h1s);
    const float4* W24 = reinterpret_cast<const float4*>(W2l);
    int q = threadIdx.x & 7;                 // lane in 8-lane group
    int node = blockIdx.x * 32 + (threadIdx.x >> 3);
    if (node >= n) return;
    int start = row_ptr[node];
    int deg = deg_arr[node];
    float4 acc = make_float4(0.f, 0.f, 0.f, 0.f);
    int jj = 0;
    for (; jj + 8 <= deg; jj += 8) {
        int c = col[start + jj + q];         // 8 lanes: one coalesced 32B load
#pragma unroll
        for (int m = 0; m < 8; ++m) {
            int s = __shfl(c, m, 8);
            float4 v = h4[(size_t)s * 8 + q];
            acc.x += v.x; acc.y += v.y; acc.z += v.z; acc.w += v.w;
        }
    }
    int rem = deg - jj;
    if (rem > 0) {
        int c = col[start + jj + (q < rem ? q : 0)];
        for (int m = 0; m < rem; ++m) {
            int s = __shfl(c, m, 8);
            float4 v = h4[(size_t)s * 8 + q];
            acc.x += v.x; acc.y += v.y; acc.z += v.z; acc.w += v.w;
        }
    }
    float ni = norm_in[node];
    const float4 b14 = reinterpret_cast<const float4*>(b1)[q];
    float4 t;
    t.x = fmaxf(acc.x * ni + b14.x, 0.f);
    t.y = fmaxf(acc.y * ni + b14.y, 0.f);
    t.z = fmaxf(acc.z * ni + b14.z, 0.f);
    t.w = fmaxf(acc.w * ni + b14.w, 0.f);
    // GEMM2: o[f] = sum_k t[k] * W2[k][f]; t distributed 4-per-lane over 8 lanes
    float4 o = make_float4(0.f, 0.f, 0.f, 0.f);
#pragma unroll
    for (int sl = 0; sl < 8; ++sl) {
        float4 tt = shfl4_8(t, sl);
        int kb = sl * 4;
        float4 w0 = W24[(kb + 0) * 8 + q];
        float4 w1 = W24[(kb + 1) * 8 + q];
        float4 w2 = W24[(kb + 2) * 8 + q];
        float4 w3 = W24[(kb + 3) * 8 + q];
        o.x += tt.x * w0.x + tt.y * w1.x + tt.z * w2.x + tt.w * w3.x;
        o.y += tt.x * w0.y + tt.y * w1.y + tt.z * w2.y + tt.w * w3.y;
        o.z += tt.x * w0.z + tt.y * w1.z + tt.z * w2.z + tt.w * w3.z;
        o.w += tt.x * w0.w + tt.y * w1.w + tt.z * w2.w + tt.w * w3.w;
    }
    float no = norm_out[node];
    o.x *= no; o.y *= no; o.z *= no; o.w *= no;
    reinterpret_cast<float4*>(h2s)[(size_t)node * 8 + q] = o;
}

// layer 2: agg + norm_in + b2 -> out
__global__ __launch_bounds__(256) void agg2_kernel(const float* __restrict__ h2s,
                                                   const int* __restrict__ row_ptr,
                                                   const int* __restrict__ deg_arr,
                                                   const int* __restrict__ col,
                                                   const float* __restrict__ norm_in,
                                                   const float* __restrict__ b2,
                                                   float* __restrict__ out, int n) {
    const float4* h4 = reinterpret_cast<const float4*>(h2s);
    int q = threadIdx.x & 7;
    int node = blockIdx.x * 32 + (threadIdx.x >> 3);
    if (node >= n) return;
    int start = row_ptr[node];
    int deg = deg_arr[node];
    float4 acc = make_float4(0.f, 0.f, 0.f, 0.f);
    int jj = 0;
    for (; jj + 8 <= deg; jj += 8) {
        int c = col[start + jj + q];
#pragma unroll
        for (int m = 0; m < 8; ++m) {
            int s = __shfl(c, m, 8);
            float4 v = h4[(size_t)s * 8 + q];
            acc.x += v.x; acc.y += v.y; acc.z += v.z; acc.w += v.w;
        }
    }
    int rem = deg - jj;
    if (rem > 0) {
        int c = col[start + jj + (q < rem ? q : 0)];
        for (int m = 0; m < rem; ++m) {
            int s = __shfl(c, m, 8);
            float4 v = h4[(size_t)s * 8 + q];
            acc.x += v.x; acc.y += v.y; acc.z += v.z; acc.w += v.w;
        }
    }
    float ni = norm_in[node];
    const float4 b24 = reinterpret_cast<const float4*>(b2)[q];
    float4 o;
    o.x = acc.x * ni + b24.x;
    o.y = acc.y * ni + b24.y;
    o.z = acc.z * ni + b24.z;
    o.w = acc.w * ni + b24.w;
    reinterpret_cast<float4*>(out)[(size_t)node * 8 + q] = o;
}

// ---------------- launch ----------------

static inline size_t align256(size_t x) { return (x + 255) & ~(size_t)255; }

extern "C" void kernel_launch(void* const* d_in, const int* in_sizes, int n_in,
                              void* d_out, int out_size, void* d_ws, size_t ws_size,
                              hipStream_t stream) {
    const float* features = (const float*)d_in[0];
    const float* W1 = (const float*)d_in[1];
    const float* b1 = (const float*)d_in[2];
    const float* W2 = (const float*)d_in[3];
    const float* b2 = (const float*)d_in[4];
    const int* src = (const int*)d_in[5];
    const int* dst = (const int*)d_in[6];
    const int E = in_sizes[5];
    const int n = N_NODES;
    float* out = (float*)d_out;

    char* ws = (char*)d_ws;
    size_t off = 0;
    float* norm_out = (float*)(ws + off); off += align256((size_t)n * 4);
    float* norm_in = (float*)(ws + off);  off += align256((size_t)n * 4);
    int* row_ptr = (int*)(ws + off);      off += align256((size_t)n * 4);
    int* deg_arr = (int*)(ws + off);      off += align256((size_t)n * 4);
    unsigned* startD = (unsigned*)(ws + off); off += align256((NBUCK + 1) * 4);
    unsigned* startS = (unsigned*)(ws + off); off += align256((NBUCK + 1) * 4);
    unsigned* totD = (unsigned*)(ws + off);   off += align256(NBUCK * 4);
    unsigned* totS = (unsigned*)(ws + off);   off += align256(NBUCK * 4);
    int* col = (int*)(ws + off);              off += align256((size_t)E * 4);  // 6.4 MB

    // region X: pairD+valS (live: part_scatter -> bucket kernels) then h2s (live: agg1 -> agg2)
    size_t regX = off;
    unsigned* pairD = (unsigned*)(ws + regX);                        // 6.4 MB
    unsigned* valS = (unsigned*)(ws + regX + (size_t)E * 4);         // 6.4 MB
    float* h2s = (float*)(ws + regX);                                // 12.8 MB
    off += align256((size_t)2 * E * 4);
    // region Y: cntD+cntS (live: part_count -> part_scatter) then h1s (live: gemm1 -> agg1)
    size_t regY = off;
    unsigned* cntD = (unsigned*)(ws + regY);                         // 100 KB
    unsigned* cntS = (unsigned*)(ws + regY + (size_t)NBLK * NBUCK * 4);
    float* h1s = (float*)(ws + regY);                                // 12.8 MB

    // phase A: partition edges by dst-bucket (pairs) and src-bucket (locals)
    part_count<<<NBLK, PART_THREADS, 0, stream>>>(src, dst, E, cntD, cntS);
    col_scan<<<NBUCK, NBLK, 0, stream>>>(cntD, totD);
    col_scan<<<NBUCK, NBLK, 0, stream>>>(cntS, totS);
    total_scan<<<1, 1024, 0, stream>>>(totD, startD);
    total_scan<<<1, 1024, 0, stream>>>(totS, startS);
    part_scatter<<<NBLK, PART_THREADS, 0, stream>>>(src, dst, E, cntD, cntS, startD, startS,
                                                    pairD, valS);

    // phase B: per-bucket counting sort -> CSR (+ norm_in), src norms
    bucket_sort<<<NBUCK, 256, 0, stream>>>(pairD, startD, col, row_ptr, deg_arr, norm_in, n);
    bucket_norms_src<<<NBUCK, 256, 0, stream>>>(valS, startS, norm_out, n);

    // layer 1 projection (+ norm_out prescale), W+Xs in LDS
    gemm1_kernel<<<(n + G1_NODES - 1) / G1_NODES, G1_BLOCK, 0, stream>>>(features, W1, norm_out,
                                                                         h1s, n);

    // gather aggregation (8 lanes/node, float4), fused epilogues
    agg1_kernel<<<(n + 31) / 32, 256, 0, stream>>>(h1s, row_ptr, deg_arr, col, norm_in,
                                                   norm_out, b1, W2, h2s, n);
    agg2_kernel<<<(n + 31) / 32, 256, 0, stream>>>(h2s, row_ptr, deg_arr, col, norm_in, b2, out, n);
}

// Round 13
// 174.963 us; speedup vs baseline: 1.1988x; 1.0010x over previous
//
#include <hip/hip_runtime.h>

#define N_NODES 100000
#define F_IN 128
#define F_HID 32
#define BN 512                  // nodes per bucket (pow2)
#define NBUCK 196               // ceil(100000/512)
#define NBLK 128                // edge partition chunks (64 entries/bucket avg -> 256B runs)
#define PART_THREADS 1024
#define G1_BLOCK 256
#define G1_NODES 64             // nodes per gemm1 block

// ---------------- phase A: bucket partition of edges (no global atomics) ----------------

__global__ __launch_bounds__(PART_THREADS) void part_count(const int* __restrict__ src,
                                                           const int* __restrict__ dst, int E,
                                                           unsigned* __restrict__ cntD,
                                                           unsigned* __restrict__ cntS) {
    __shared__ unsigned cd[NBUCK], cs[NBUCK];
    for (int i = threadIdx.x; i < NBUCK; i += PART_THREADS) { cd[i] = 0; cs[i] = 0; }
    __syncthreads();
    int chunk = (E + NBLK - 1) / NBLK;
    int e0 = blockIdx.x * chunk, e1 = min(E, e0 + chunk);
    for (int e = e0 + threadIdx.x; e < e1; e += PART_THREADS) {
        atomicAdd(&cd[((unsigned)dst[e]) >> 9], 1u);   // LDS atomic
        atomicAdd(&cs[((unsigned)src[e]) >> 9], 1u);
    }
    __syncthreads();
    unsigned* od = cntD + (size_t)blockIdx.x * NBUCK;
    unsigned* os = cntS + (size_t)blockIdx.x * NBUCK;
    for (int i = threadIdx.x; i < NBUCK; i += PART_THREADS) { od[i] = cd[i]; os[i] = cs[i]; }
}

// per-bucket exclusive scan over blocks (in place); totals[k] = bucket size
__global__ __launch_bounds__(NBLK) void col_scan(unsigned* __restrict__ cnt,
                                                 unsigned* __restrict__ totals) {
    __shared__ unsigned buf[2][NBLK];
    int k = blockIdx.x, t = threadIdx.x;
    unsigned v = cnt[(size_t)t * NBUCK + k];
    buf[0][t] = v;
    __syncthreads();
    int cur = 0;
    for (int off = 1; off < NBLK; off <<= 1) {
        unsigned x = buf[cur][t];
        if (t >= off) x += buf[cur][t - off];
        buf[cur ^ 1][t] = x;
        cur ^= 1;
        __syncthreads();
    }
    cnt[(size_t)t * NBUCK + k] = buf[cur][t] - v;  // exclusive over blocks
    if (t == NBLK - 1) totals[k] = buf[cur][NBLK - 1];
}

// exclusive scan of bucket totals -> start[0..NBUCK] (start[NBUCK] = E)
__global__ __launch_bounds__(1024) void total_scan(const unsigned* __restrict__ totals,
                                                   unsigned* __restrict__ start) {
    __shared__ unsigned buf[2][1024];
    int t = threadIdx.x;
    buf[0][t] = (t < NBUCK) ? totals[t] : 0;
    __syncthreads();
    int cur = 0;
    for (int off = 1; off < 1024; off <<= 1) {
        unsigned x = buf[cur][t];
        if (t >= off) x += buf[cur][t - off];
        buf[cur ^ 1][t] = x;
        cur ^= 1;
        __syncthreads();
    }
    if (t < NBUCK) start[t + 1] = buf[cur][t];
    if (t == 0) start[0] = 0;
}

// scatter edges into bucket-partitioned layout; slots disjoint by construction
__global__ __launch_bounds__(PART_THREADS) void part_scatter(const int* __restrict__ src,
                                                             const int* __restrict__ dst, int E,
                                                             const unsigned* __restrict__ cntD,
                                                             const unsigned* __restrict__ cntS,
                                                             const unsigned* __restrict__ startD,
                                                             const unsigned* __restrict__ startS,
                                                             unsigned* __restrict__ pairD,
                                                             unsigned* __restrict__ valS) {
    __shared__ unsigned curD[NBUCK], curS[NBUCK];
    for (int i = threadIdx.x; i < NBUCK; i += PART_THREADS) { curD[i] = 0; curS[i] = 0; }
    __syncthreads();
    int chunk = (E + NBLK - 1) / NBLK;
    int e0 = blockIdx.x * chunk, e1 = min(E, e0 + chunk);
    const unsigned* bd = cntD + (size_t)blockIdx.x * NBUCK;
    const unsigned* bs = cntS + (size_t)blockIdx.x * NBUCK;
    for (int e = e0 + threadIdx.x; e < e1; e += PART_THREADS) {
        unsigned s = (unsigned)src[e], d = (unsigned)dst[e];
        unsigned kd = d >> 9, ks = s >> 9;
        unsigned rd = atomicAdd(&curD[kd], 1u);                 // LDS rank
        pairD[startD[kd] + bd[kd] + rd] = s | ((d & 511u) << 17);
        unsigned rs = atomicAdd(&curS[ks], 1u);
        valS[startS[ks] + bs[ks] + rs] = s & 511u;
    }
}

// ---------------- phase B: per-bucket counting sort -> full CSR (no global atomics) ----------
// BN=512 bins, 256 threads: each thread owns bins t and t+256.

__global__ __launch_bounds__(256) void bucket_sort(const unsigned* __restrict__ pairD,
                                                   const unsigned* __restrict__ startD,
                                                   int* __restrict__ col, int* __restrict__ row_ptr,
                                                   int* __restrict__ deg_arr,
                                                   float* __restrict__ norm_in, int n) {
    __shared__ unsigned cnt[BN];
    __shared__ unsigned base[BN];
    __shared__ unsigned sbuf[2][BN];
    int t = threadIdx.x;
    cnt[t] = 0; cnt[t + 256] = 0;
    __syncthreads();
    int k = blockIdx.x;
    unsigned a0 = startD[k], a1 = startD[k + 1];
    for (unsigned i = a0 + t; i < a1; i += 256)
        atomicAdd(&cnt[(pairD[i] >> 17) & (BN - 1)], 1u);
    __syncthreads();
    unsigned v0 = cnt[t], v1 = cnt[t + 256];
    sbuf[0][t] = v0; sbuf[0][t + 256] = v1;
    __syncthreads();
    int cur = 0;
    for (int off = 1; off < BN; off <<= 1) {
        unsigned x0 = sbuf[cur][t];
        if (t >= off) x0 += sbuf[cur][t - off];
        unsigned x1 = sbuf[cur][t + 256] + sbuf[cur][t + 256 - off];  // t+256 >= off always
        sbuf[cur ^ 1][t] = x0;
        sbuf[cur ^ 1][t + 256] = x1;
        cur ^= 1;
        __syncthreads();
    }
    {
        base[t] = a0 + sbuf[cur][t] - v0;
        base[t + 256] = a0 + sbuf[cur][t + 256] - v1;
        int node0 = k * BN + t, node1 = k * BN + t + 256;
        if (node0 < n) {
            row_ptr[node0] = (int)base[t];
            deg_arr[node0] = (int)v0;
            norm_in[node0] = rsqrtf((float)(v0 > 1u ? v0 : 1u));
        }
        if (node1 < n) {
            row_ptr[node1] = (int)base[t + 256];
            deg_arr[node1] = (int)v1;
            norm_in[node1] = rsqrtf((float)(v1 > 1u ? v1 : 1u));
        }
        cnt[t] = 0; cnt[t + 256] = 0;
    }
    __syncthreads();
    for (unsigned i = a0 + t; i < a1; i += 256) {
        unsigned pv = pairD[i];
        unsigned l = (pv >> 17) & (BN - 1);
        unsigned r = atomicAdd(&cnt[l], 1u);   // LDS rank
        col[base[l] + r] = (int)(pv & 0x1FFFFu);
    }
}

// src-side degree -> norm_out
__global__ __launch_bounds__(256) void bucket_norms_src(const unsigned* __restrict__ valS,
                                                        const unsigned* __restrict__ startS,
                                                        float* __restrict__ norm_out, int n) {
    __shared__ unsigned cnt[BN];
    int t = threadIdx.x;
    cnt[t] = 0; cnt[t + 256] = 0;
    __syncthreads();
    int k = blockIdx.x;
    unsigned a0 = startS[k], a1 = startS[k + 1];
    for (unsigned i = a0 + t; i < a1; i += 256)
        atomicAdd(&cnt[valS[i]], 1u);
    __syncthreads();
#pragma unroll
    for (int h = 0; h < 2; ++h) {
        int l = t + h * 256;
        int node = k * BN + l;
        if (node < n) {
            unsigned c = cnt[l];
            norm_out[node] = rsqrtf((float)(c > 1u ? c : 1u));
        }
    }
}

// ---------------- layer-1 projection: W + padded Xs both in LDS (49.9 KB) ----------------
// 256 threads / 64 nodes: group g (0..31) owns rows g, g+32. X banks: (4g+4k4)%32 tiles
// all 32 banks across the wave's 8 groups; W banks: 4q spans 32 banks, groups broadcast.

__device__ __forceinline__ void fma4(float4& a, float s, float4 w) {
    a.x += s * w.x; a.y += s * w.y; a.z += s * w.z; a.w += s * w.w;
}

__global__ __launch_bounds__(G1_BLOCK) void gemm1_kernel(const float* __restrict__ x,
                                                         const float* __restrict__ W,
                                                         const float* __restrict__ norm_out,
                                                         float* __restrict__ h, int n) {
    __shared__ float4 Xs[G1_NODES * 33];  // 33792 B, padded rows
    __shared__ float4 Ws[F_IN * 8];       // 16384 B
    const float4* W4 = reinterpret_cast<const float4*>(W);
    for (int i = threadIdx.x; i < F_IN * 8; i += G1_BLOCK) Ws[i] = W4[i];
    int nb = blockIdx.x * G1_NODES;
    int nrows = n - nb; if (nrows > G1_NODES) nrows = G1_NODES;
    const float4* x4 = reinterpret_cast<const float4*>(x + (size_t)nb * F_IN);
    for (int i = threadIdx.x; i < nrows * 32; i += G1_BLOCK)
        Xs[(i >> 5) * 33 + (i & 31)] = x4[i];
    __syncthreads();
    int q = threadIdx.x & 7;      // output quad: j = 4q..4q+3
    int g = threadIdx.x >> 3;     // group 0..31; nodes g, g+32
    float4 acc0 = make_float4(0.f, 0.f, 0.f, 0.f);
    float4 acc1 = acc0;
#pragma unroll 4
    for (int k4 = 0; k4 < 32; ++k4) {
        float4 xv0 = Xs[(g + 0) * 33 + k4];
        float4 xv1 = Xs[(g + 32) * 33 + k4];
        float4 w0 = Ws[(k4 * 4 + 0) * 8 + q];
        float4 w1 = Ws[(k4 * 4 + 1) * 8 + q];
        float4 w2 = Ws[(k4 * 4 + 2) * 8 + q];
        float4 w3 = Ws[(k4 * 4 + 3) * 8 + q];
        fma4(acc0, xv0.x, w0); fma4(acc0, xv0.y, w1); fma4(acc0, xv0.z, w2); fma4(acc0, xv0.w, w3);
        fma4(acc1, xv1.x, w0); fma4(acc1, xv1.y, w1); fma4(acc1, xv1.z, w2); fma4(acc1, xv1.w, w3);
    }
    float4* h4 = reinterpret_cast<float4*>(h);
    float4 accs[2] = {acc0, acc1};
#pragma unroll
    for (int i = 0; i < 2; ++i) {
        int node = nb + g + 32 * i;
        if (node < n) {
            float no = norm_out[node];
            float4 o = accs[i];
            o.x *= no; o.y *= no; o.z *= no; o.w *= no;
            h4[(size_t)node * 8 + q] = o;
        }
    }
}

// ---------------- gather aggregation: 8 lanes/node, float4/lane, 8-edge unroll --------------

__device__ __forceinline__ float4 shfl4_8(float4 v, int sl) {
    float4 r;
    r.x = __shfl(v.x, sl, 8);
    r.y = __shfl(v.y, sl, 8);
    r.z = __shfl(v.z, sl, 8);
    r.w = __shfl(v.w, sl, 8);
    return r;
}

// layer 1: agg + norm_in + b1 + relu, GEMM2 (8-lane shfl), prescale norm_out -> h2s
__global__ __launch_bounds__(256) void agg1_kernel(const float* __restrict__ h1s,
                                                   const int* __restrict__ row_ptr,
                                                   const int* __restrict__ deg_arr,
                                                   const int* __restrict__ col,
                                                   const float* __restrict__ norm_in,
                                                   const float* __restrict__ norm_out,
                                                   const float* __restrict__ b1,
                                                   const float* __restrict__ W2,
                                                   float* __restrict__ h2s, int n) {
    __shared__ float W2l[F_HID * F_HID];  // row k holds W2[k][0..31]
    for (int i = threadIdx.x; i < F_HID * F_HID; i += 256) W2l[i] = W2[i];
    __syncthreads();
    const float4* h4 = reinterpret_cast<const float4*>(h1s);
    const float4* W24 = reinterpret_cast<const float4*>(W2l);
    int q = threadIdx.x & 7;                 // lane in 8-lane group
    int node = blockIdx.x * 32 + (threadIdx.x >> 3);
    if (node >= n) return;
    int start = row_ptr[node];
    int deg = deg_arr[node];
    float4 acc = make_float4(0.f, 0.f, 0.f, 0.f);
    int jj = 0;
    for (; jj + 8 <= deg; jj += 8) {
        int c = col[start + jj + q];         // 8 lanes: one coalesced 32B load
#pragma unroll
        for (int m = 0; m < 8; ++m) {
            int s = __shfl(c, m, 8);
            float4 v = h4[(size_t)s * 8 + q];
            acc.x += v.x; acc.y += v.y; acc.z += v.z; acc.w += v.w;
        }
    }
    int rem = deg - jj;
    if (rem > 0) {
        int c = col[start + jj + (q < rem ? q : 0)];
        for (int m = 0; m < rem; ++m) {
            int s = __shfl(c, m, 8);
            float4 v = h4[(size_t)s * 8 + q];
            acc.x += v.x; acc.y += v.y; acc.z += v.z; acc.w += v.w;
        }
    }
    float ni = norm_in[node];
    const float4 b14 = reinterpret_cast<const float4*>(b1)[q];
    float4 t;
    t.x = fmaxf(acc.x * ni + b14.x, 0.f);
    t.y = fmaxf(acc.y * ni + b14.y, 0.f);
    t.z = fmaxf(acc.z * ni + b14.z, 0.f);
    t.w = fmaxf(acc.w * ni + b14.w, 0.f);
    // GEMM2: o[f] = sum_k t[k] * W2[k][f]; t distributed 4-per-lane over 8 lanes
    float4 o = make_float4(0.f, 0.f, 0.f, 0.f);
#pragma unroll
    for (int sl = 0; sl < 8; ++sl) {
        float4 tt = shfl4_8(t, sl);
        int kb = sl * 4;
        float4 w0 = W24[(kb + 0) * 8 + q];
        float4 w1 = W24[(kb + 1) * 8 + q];
        float4 w2 = W24[(kb + 2) * 8 + q];
        float4 w3 = W24[(kb + 3) * 8 + q];
        o.x += tt.x * w0.x + tt.y * w1.x + tt.z * w2.x + tt.w * w3.x;
        o.y += tt.x * w0.y + tt.y * w1.y + tt.z * w2.y + tt.w * w3.y;
        o.z += tt.x * w0.z + tt.y * w1.z + tt.z * w2.z + tt.w * w3.z;
        o.w += tt.x * w0.w + tt.y * w1.w + tt.z * w2.w + tt.w * w3.w;
    }
    float no = norm_out[node];
    o.x *= no; o.y *= no; o.z *= no; o.w *= no;
    reinterpret_cast<float4*>(h2s)[(size_t)node * 8 + q] = o;
}

// layer 2: agg + norm_in + b2 -> out
__global__ __launch_bounds__(256) void agg2_kernel(const float* __restrict__ h2s,
                                                   const int* __restrict__ row_ptr,
                                                   const int* __restrict__ deg_arr,
                                                   const int* __restrict__ col,
                                                   const float* __restrict__ norm_in,
                                                   const float* __restrict__ b2,
                                                   float* __restrict__ out, int n) {
    const float4* h4 = reinterpret_cast<const float4*>(h2s);
    int q = threadIdx.x & 7;
    int node = blockIdx.x * 32 + (threadIdx.x >> 3);
    if (node >= n) return;
    int start = row_ptr[node];
    int deg = deg_arr[node];
    float4 acc = make_float4(0.f, 0.f, 0.f, 0.f);
    int jj = 0;
    for (; jj + 8 <= deg; jj += 8) {
        int c = col[start + jj + q];
#pragma unroll
        for (int m = 0; m < 8; ++m) {
            int s = __shfl(c, m, 8);
            float4 v = h4[(size_t)s * 8 + q];
            acc.x += v.x; acc.y += v.y; acc.z += v.z; acc.w += v.w;
        }
    }
    int rem = deg - jj;
    if (rem > 0) {
        int c = col[start + jj + (q < rem ? q : 0)];
        for (int m = 0; m < rem; ++m) {
            int s = __shfl(c, m, 8);
            float4 v = h4[(size_t)s * 8 + q];
            acc.x += v.x; acc.y += v.y; acc.z += v.z; acc.w += v.w;
        }
    }
    float ni = norm_in[node];
    const float4 b24 = reinterpret_cast<const float4*>(b2)[q];
    float4 o;
    o.x = acc.x * ni + b24.x;
    o.y = acc.y * ni + b24.y;
    o.z = acc.z * ni + b24.z;
    o.w = acc.w * ni + b24.w;
    reinterpret_cast<float4*>(out)[(size_t)node * 8 + q] = o;
}

// ---------------- launch ----------------

static inline size_t align256(size_t x) { return (x + 255) & ~(size_t)255; }

extern "C" void kernel_launch(void* const* d_in, const int* in_sizes, int n_in,
                              void* d_out, int out_size, void* d_ws, size_t ws_size,
                              hipStream_t stream) {
    const float* features = (const float*)d_in[0];
    const float* W1 = (const float*)d_in[1];
    const float* b1 = (const float*)d_in[2];
    const float* W2 = (const float*)d_in[3];
    const float* b2 = (const float*)d_in[4];
    const int* src = (const int*)d_in[5];
    const int* dst = (const int*)d_in[6];
    const int E = in_sizes[5];
    const int n = N_NODES;
    float* out = (float*)d_out;

    char* ws = (char*)d_ws;
    size_t off = 0;
    float* norm_out = (float*)(ws + off); off += align256((size_t)n * 4);
    float* norm_in = (float*)(ws + off);  off += align256((size_t)n * 4);
    int* row_ptr = (int*)(ws + off);      off += align256((size_t)n * 4);
    int* deg_arr = (int*)(ws + off);      off += align256((size_t)n * 4);
    unsigned* startD = (unsigned*)(ws + off); off += align256((NBUCK + 1) * 4);
    unsigned* startS = (unsigned*)(ws + off); off += align256((NBUCK + 1) * 4);
    unsigned* totD = (unsigned*)(ws + off);   off += align256(NBUCK * 4);
    unsigned* totS = (unsigned*)(ws + off);   off += align256(NBUCK * 4);
    int* col = (int*)(ws + off);              off += align256((size_t)E * 4);  // 6.4 MB

    // region X: pairD+valS (live: part_scatter -> bucket kernels) then h2s (live: agg1 -> agg2)
    size_t regX = off;
    unsigned* pairD = (unsigned*)(ws + regX);                        // 6.4 MB
    unsigned* valS = (unsigned*)(ws + regX + (size_t)E * 4);         // 6.4 MB
    float* h2s = (float*)(ws + regX);                                // 12.8 MB
    off += align256((size_t)2 * E * 4);
    // region Y: cntD+cntS (live: part_count -> part_scatter) then h1s (live: gemm1 -> agg1)
    size_t regY = off;
    unsigned* cntD = (unsigned*)(ws + regY);                         // 100 KB
    unsigned* cntS = (unsigned*)(ws + regY + (size_t)NBLK * NBUCK * 4);
    float* h1s = (float*)(ws + regY);                                // 12.8 MB

    // phase A: partition edges by dst-bucket (pairs) and src-bucket (locals)
    part_count<<<NBLK, PART_THREADS, 0, stream>>>(src, dst, E, cntD, cntS);
    col_scan<<<NBUCK, NBLK, 0, stream>>>(cntD, totD);
    col_scan<<<NBUCK, NBLK, 0, stream>>>(cntS, totS);
    total_scan<<<1, 1024, 0, stream>>>(totD, startD);
    total_scan<<<1, 1024, 0, stream>>>(totS, startS);
    part_scatter<<<NBLK, PART_THREADS, 0, stream>>>(src, dst, E, cntD, cntS, startD, startS,
                                                    pairD, valS);

    // phase B: per-bucket counting sort -> CSR (+ norm_in), src norms
    bucket_sort<<<NBUCK, 256, 0, stream>>>(pairD, startD, col, row_ptr, deg_arr, norm_in, n);
    bucket_norms_src<<<NBUCK, 256, 0, stream>>>(valS, startS, norm_out, n);

    // layer 1 projection (+ norm_out prescale), W+Xs in LDS
    gemm1_kernel<<<(n + G1_NODES - 1) / G1_NODES, G1_BLOCK, 0, stream>>>(features, W1, norm_out,
                                                                         h1s, n);

    // gather aggregation (8 lanes/node, float4), fused epilogues
    agg1_kernel<<<(n + 31) / 32, 256, 0, stream>>>(h1s, row_ptr, deg_arr, col, norm_in,
                                                   norm_out, b1, W2, h2s, n);
    agg2_kernel<<<(n + 31) / 32, 256, 0, stream>>>(h2s, row_ptr, deg_arr, col, norm_in, b2, out, n);
}

// Round 14
// 158.457 us; speedup vs baseline: 1.3237x; 1.1042x over previous
//
#include <hip/hip_runtime.h>
#include <hip/hip_fp16.h>

#define N_NODES 100000
#define F_IN 128
#define F_HID 32
#define BN 512                  // nodes per bucket (pow2)
#define NBUCK 196               // ceil(100000/512)
#define NBLK 128                // edge partition chunks
#define PART_THREADS 1024
#define G1_BLOCK 256
#define G1_NODES 64             // nodes per gemm1 block

// ---------------- phase A: bucket partition of edges (no global atomics) ----------------

__global__ __launch_bounds__(PART_THREADS) void part_count(const int* __restrict__ src,
                                                           const int* __restrict__ dst, int E,
                                                           unsigned* __restrict__ cntD,
                                                           unsigned* __restrict__ cntS) {
    __shared__ unsigned cd[NBUCK], cs[NBUCK];
    for (int i = threadIdx.x; i < NBUCK; i += PART_THREADS) { cd[i] = 0; cs[i] = 0; }
    __syncthreads();
    int chunk = (E + NBLK - 1) / NBLK;
    int e0 = blockIdx.x * chunk, e1 = min(E, e0 + chunk);
    for (int e = e0 + threadIdx.x; e < e1; e += PART_THREADS) {
        atomicAdd(&cd[((unsigned)dst[e]) >> 9], 1u);   // LDS atomic
        atomicAdd(&cs[((unsigned)src[e]) >> 9], 1u);
    }
    __syncthreads();
    unsigned* od = cntD + (size_t)blockIdx.x * NBUCK;
    unsigned* os = cntS + (size_t)blockIdx.x * NBUCK;
    for (int i = threadIdx.x; i < NBUCK; i += PART_THREADS) { od[i] = cd[i]; os[i] = cs[i]; }
}

// per-bucket exclusive scan over blocks (in place); totals[k] = bucket size
__global__ __launch_bounds__(NBLK) void col_scan(unsigned* __restrict__ cnt,
                                                 unsigned* __restrict__ totals) {
    __shared__ unsigned buf[2][NBLK];
    int k = blockIdx.x, t = threadIdx.x;
    unsigned v = cnt[(size_t)t * NBUCK + k];
    buf[0][t] = v;
    __syncthreads();
    int cur = 0;
    for (int off = 1; off < NBLK; off <<= 1) {
        unsigned x = buf[cur][t];
        if (t >= off) x += buf[cur][t - off];
        buf[cur ^ 1][t] = x;
        cur ^= 1;
        __syncthreads();
    }
    cnt[(size_t)t * NBUCK + k] = buf[cur][t] - v;  // exclusive over blocks
    if (t == NBLK - 1) totals[k] = buf[cur][NBLK - 1];
}

// exclusive scan of bucket totals -> start[0..NBUCK] (start[NBUCK] = E)
__global__ __launch_bounds__(1024) void total_scan(const unsigned* __restrict__ totals,
                                                   unsigned* __restrict__ start) {
    __shared__ unsigned buf[2][1024];
    int t = threadIdx.x;
    buf[0][t] = (t < NBUCK) ? totals[t] : 0;
    __syncthreads();
    int cur = 0;
    for (int off = 1; off < 1024; off <<= 1) {
        unsigned x = buf[cur][t];
        if (t >= off) x += buf[cur][t - off];
        buf[cur ^ 1][t] = x;
        cur ^= 1;
        __syncthreads();
    }
    if (t < NBUCK) start[t + 1] = buf[cur][t];
    if (t == 0) start[0] = 0;
}

// scatter edges into bucket-partitioned layout; slots disjoint by construction
__global__ __launch_bounds__(PART_THREADS) void part_scatter(const int* __restrict__ src,
                                                             const int* __restrict__ dst, int E,
                                                             const unsigned* __restrict__ cntD,
                                                             const unsigned* __restrict__ cntS,
                                                             const unsigned* __restrict__ startD,
                                                             const unsigned* __restrict__ startS,
                                                             unsigned* __restrict__ pairD,
                                                             unsigned* __restrict__ valS) {
    __shared__ unsigned curD[NBUCK], curS[NBUCK];
    for (int i = threadIdx.x; i < NBUCK; i += PART_THREADS) { curD[i] = 0; curS[i] = 0; }
    __syncthreads();
    int chunk = (E + NBLK - 1) / NBLK;
    int e0 = blockIdx.x * chunk, e1 = min(E, e0 + chunk);
    const unsigned* bd = cntD + (size_t)blockIdx.x * NBUCK;
    const unsigned* bs = cntS + (size_t)blockIdx.x * NBUCK;
    for (int e = e0 + threadIdx.x; e < e1; e += PART_THREADS) {
        unsigned s = (unsigned)src[e], d = (unsigned)dst[e];
        unsigned kd = d >> 9, ks = s >> 9;
        unsigned rd = atomicAdd(&curD[kd], 1u);                 // LDS rank
        pairD[startD[kd] + bd[kd] + rd] = s | ((d & 511u) << 17);
        unsigned rs = atomicAdd(&curS[ks], 1u);
        valS[startS[ks] + bs[ks] + rs] = s & 511u;
    }
}

// ---------------- phase B: per-bucket counting sort -> full CSR (no global atomics) ----------

__global__ __launch_bounds__(256) void bucket_sort(const unsigned* __restrict__ pairD,
                                                   const unsigned* __restrict__ startD,
                                                   int* __restrict__ col, int* __restrict__ row_ptr,
                                                   int* __restrict__ deg_arr,
                                                   float* __restrict__ norm_in, int n) {
    __shared__ unsigned cnt[BN];
    __shared__ unsigned base[BN];
    __shared__ unsigned sbuf[2][BN];
    int t = threadIdx.x;
    cnt[t] = 0; cnt[t + 256] = 0;
    __syncthreads();
    int k = blockIdx.x;
    unsigned a0 = startD[k], a1 = startD[k + 1];
    for (unsigned i = a0 + t; i < a1; i += 256)
        atomicAdd(&cnt[(pairD[i] >> 17) & (BN - 1)], 1u);
    __syncthreads();
    unsigned v0 = cnt[t], v1 = cnt[t + 256];
    sbuf[0][t] = v0; sbuf[0][t + 256] = v1;
    __syncthreads();
    int cur = 0;
    for (int off = 1; off < BN; off <<= 1) {
        unsigned x0 = sbuf[cur][t];
        if (t >= off) x0 += sbuf[cur][t - off];
        unsigned x1 = sbuf[cur][t + 256] + sbuf[cur][t + 256 - off];  // t+256 >= off always
        sbuf[cur ^ 1][t] = x0;
        sbuf[cur ^ 1][t + 256] = x1;
        cur ^= 1;
        __syncthreads();
    }
    {
        base[t] = a0 + sbuf[cur][t] - v0;
        base[t + 256] = a0 + sbuf[cur][t + 256] - v1;
        int node0 = k * BN + t, node1 = k * BN + t + 256;
        if (node0 < n) {
            row_ptr[node0] = (int)base[t];
            deg_arr[node0] = (int)v0;
            norm_in[node0] = rsqrtf((float)(v0 > 1u ? v0 : 1u));
        }
        if (node1 < n) {
            row_ptr[node1] = (int)base[t + 256];
            deg_arr[node1] = (int)v1;
            norm_in[node1] = rsqrtf((float)(v1 > 1u ? v1 : 1u));
        }
        cnt[t] = 0; cnt[t + 256] = 0;
    }
    __syncthreads();
    for (unsigned i = a0 + t; i < a1; i += 256) {
        unsigned pv = pairD[i];
        unsigned l = (pv >> 17) & (BN - 1);
        unsigned r = atomicAdd(&cnt[l], 1u);   // LDS rank
        col[base[l] + r] = (int)(pv & 0x1FFFFu);
    }
}

// src-side degree -> norm_out
__global__ __launch_bounds__(256) void bucket_norms_src(const unsigned* __restrict__ valS,
                                                        const unsigned* __restrict__ startS,
                                                        float* __restrict__ norm_out, int n) {
    __shared__ unsigned cnt[BN];
    int t = threadIdx.x;
    cnt[t] = 0; cnt[t + 256] = 0;
    __syncthreads();
    int k = blockIdx.x;
    unsigned a0 = startS[k], a1 = startS[k + 1];
    for (unsigned i = a0 + t; i < a1; i += 256)
        atomicAdd(&cnt[valS[i]], 1u);
    __syncthreads();
#pragma unroll
    for (int h = 0; h < 2; ++h) {
        int l = t + h * 256;
        int node = k * BN + l;
        if (node < n) {
            unsigned c = cnt[l];
            norm_out[node] = rsqrtf((float)(c > 1u ? c : 1u));
        }
    }
}

// ---------------- fp16 pack/unpack helpers ----------------

__device__ __forceinline__ float2 pack_half4(float a, float b, float c, float d) {
    __half2 h0 = __floats2half2_rn(a, b);
    __half2 h1 = __floats2half2_rn(c, d);
    float2 r;
    r.x = *reinterpret_cast<float*>(&h0);
    r.y = *reinterpret_cast<float*>(&h1);
    return r;
}

__device__ __forceinline__ void unpack_half4(float2 v, float4& acc) {
    __half2 ha = *reinterpret_cast<__half2*>(&v.x);
    __half2 hb = *reinterpret_cast<__half2*>(&v.y);
    float2 fa = __half22float2(ha);
    float2 fb = __half22float2(hb);
    acc.x += fa.x; acc.y += fa.y; acc.z += fb.x; acc.w += fb.y;
}

// ---------------- layer-1 projection: W + padded Xs in LDS; fp16 output ----------------

__device__ __forceinline__ void fma4(float4& a, float s, float4 w) {
    a.x += s * w.x; a.y += s * w.y; a.z += s * w.z; a.w += s * w.w;
}

__global__ __launch_bounds__(G1_BLOCK) void gemm1_kernel(const float* __restrict__ x,
                                                         const float* __restrict__ W,
                                                         const float* __restrict__ norm_out,
                                                         float2* __restrict__ hh, int n) {
    __shared__ float4 Xs[G1_NODES * 33];  // 33792 B, padded rows
    __shared__ float4 Ws[F_IN * 8];       // 16384 B
    const float4* W4 = reinterpret_cast<const float4*>(W);
    for (int i = threadIdx.x; i < F_IN * 8; i += G1_BLOCK) Ws[i] = W4[i];
    int nb = blockIdx.x * G1_NODES;
    int nrows = n - nb; if (nrows > G1_NODES) nrows = G1_NODES;
    const float4* x4 = reinterpret_cast<const float4*>(x + (size_t)nb * F_IN);
    for (int i = threadIdx.x; i < nrows * 32; i += G1_BLOCK)
        Xs[(i >> 5) * 33 + (i & 31)] = x4[i];
    __syncthreads();
    int q = threadIdx.x & 7;      // output quad: j = 4q..4q+3
    int g = threadIdx.x >> 3;     // group 0..31; nodes g, g+32
    float4 acc0 = make_float4(0.f, 0.f, 0.f, 0.f);
    float4 acc1 = acc0;
#pragma unroll 4
    for (int k4 = 0; k4 < 32; ++k4) {
        float4 xv0 = Xs[(g + 0) * 33 + k4];
        float4 xv1 = Xs[(g + 32) * 33 + k4];
        float4 w0 = Ws[(k4 * 4 + 0) * 8 + q];
        float4 w1 = Ws[(k4 * 4 + 1) * 8 + q];
        float4 w2 = Ws[(k4 * 4 + 2) * 8 + q];
        float4 w3 = Ws[(k4 * 4 + 3) * 8 + q];
        fma4(acc0, xv0.x, w0); fma4(acc0, xv0.y, w1); fma4(acc0, xv0.z, w2); fma4(acc0, xv0.w, w3);
        fma4(acc1, xv1.x, w0); fma4(acc1, xv1.y, w1); fma4(acc1, xv1.z, w2); fma4(acc1, xv1.w, w3);
    }
    float4 accs[2] = {acc0, acc1};
#pragma unroll
    for (int i = 0; i < 2; ++i) {
        int node = nb + g + 32 * i;
        if (node < n) {
            float no = norm_out[node];
            float4 o = accs[i];
            hh[(size_t)node * 8 + q] = pack_half4(o.x * no, o.y * no, o.z * no, o.w * no);
        }
    }
}

// ---------------- gather aggregation: 8 lanes/node, fp16 half4/lane, 8-edge unroll ----------

__device__ __forceinline__ float4 shfl4_8(float4 v, int sl) {
    float4 r;
    r.x = __shfl(v.x, sl, 8);
    r.y = __shfl(v.y, sl, 8);
    r.z = __shfl(v.z, sl, 8);
    r.w = __shfl(v.w, sl, 8);
    return r;
}

// layer 1: agg + norm_in + b1 + relu, GEMM2 (8-lane shfl), prescale norm_out -> h2h (fp16)
__global__ __launch_bounds__(256) void agg1_kernel(const float2* __restrict__ h1h,
                                                   const int* __restrict__ row_ptr,
                                                   const int* __restrict__ deg_arr,
                                                   const int* __restrict__ col,
                                                   const float* __restrict__ norm_in,
                                                   const float* __restrict__ norm_out,
                                                   const float* __restrict__ b1,
                                                   const float* __restrict__ W2,
                                                   float2* __restrict__ h2h, int n) {
    __shared__ float W2l[F_HID * F_HID];  // row k holds W2[k][0..31]
    for (int i = threadIdx.x; i < F_HID * F_HID; i += 256) W2l[i] = W2[i];
    __syncthreads();
    const float4* W24 = reinterpret_cast<const float4*>(W2l);
    int q = threadIdx.x & 7;                 // lane in 8-lane group
    int node = blockIdx.x * 32 + (threadIdx.x >> 3);
    if (node >= n) return;
    int start = row_ptr[node];
    int deg = deg_arr[node];
    float4 acc = make_float4(0.f, 0.f, 0.f, 0.f);
    int jj = 0;
    for (; jj + 8 <= deg; jj += 8) {
        int c = col[start + jj + q];         // 8 lanes: one coalesced 32B load
#pragma unroll
        for (int m = 0; m < 8; ++m) {
            int s = __shfl(c, m, 8);
            float2 v = h1h[(size_t)s * 8 + q];
            unpack_half4(v, acc);
        }
    }
    int rem = deg - jj;
    if (rem > 0) {
        int c = col[start + jj + (q < rem ? q : 0)];
        for (int m = 0; m < rem; ++m) {
            int s = __shfl(c, m, 8);
            float2 v = h1h[(size_t)s * 8 + q];
            unpack_half4(v, acc);
        }
    }
    float ni = norm_in[node];
    const float4 b14 = reinterpret_cast<const float4*>(b1)[q];
    float4 t;
    t.x = fmaxf(acc.x * ni + b14.x, 0.f);
    t.y = fmaxf(acc.y * ni + b14.y, 0.f);
    t.z = fmaxf(acc.z * ni + b14.z, 0.f);
    t.w = fmaxf(acc.w * ni + b14.w, 0.f);
    // GEMM2: o[f] = sum_k t[k] * W2[k][f]; t distributed 4-per-lane over 8 lanes
    float4 o = make_float4(0.f, 0.f, 0.f, 0.f);
#pragma unroll
    for (int sl = 0; sl < 8; ++sl) {
        float4 tt = shfl4_8(t, sl);
        int kb = sl * 4;
        float4 w0 = W24[(kb + 0) * 8 + q];
        float4 w1 = W24[(kb + 1) * 8 + q];
        float4 w2 = W24[(kb + 2) * 8 + q];
        float4 w3 = W24[(kb + 3) * 8 + q];
        o.x += tt.x * w0.x + tt.y * w1.x + tt.z * w2.x + tt.w * w3.x;
        o.y += tt.x * w0.y + tt.y * w1.y + tt.z * w2.y + tt.w * w3.y;
        o.z += tt.x * w0.z + tt.y * w1.z + tt.z * w2.z + tt.w * w3.z;
        o.w += tt.x * w0.w + tt.y * w1.w + tt.z * w2.w + tt.w * w3.w;
    }
    float no = norm_out[node];
    h2h[(size_t)node * 8 + q] = pack_half4(o.x * no, o.y * no, o.z * no, o.w * no);
}

// layer 2: agg + norm_in + b2 -> out (fp32)
__global__ __launch_bounds__(256) void agg2_kernel(const float2* __restrict__ h2h,
                                                   const int* __restrict__ row_ptr,
                                                   const int* __restrict__ deg_arr,
                                                   const int* __restrict__ col,
                                                   const float* __restrict__ norm_in,
                                                   const float* __restrict__ b2,
                                                   float* __restrict__ out, int n) {
    int q = threadIdx.x & 7;
    int node = blockIdx.x * 32 + (threadIdx.x >> 3);
    if (node >= n) return;
    int start = row_ptr[node];
    int deg = deg_arr[node];
    float4 acc = make_float4(0.f, 0.f, 0.f, 0.f);
    int jj = 0;
    for (; jj + 8 <= deg; jj += 8) {
        int c = col[start + jj + q];
#pragma unroll
        for (int m = 0; m < 8; ++m) {
            int s = __shfl(c, m, 8);
            float2 v = h2h[(size_t)s * 8 + q];
            unpack_half4(v, acc);
        }
    }
    int rem = deg - jj;
    if (rem > 0) {
        int c = col[start + jj + (q < rem ? q : 0)];
        for (int m = 0; m < rem; ++m) {
            int s = __shfl(c, m, 8);
            float2 v = h2h[(size_t)s * 8 + q];
            unpack_half4(v, acc);
        }
    }
    float ni = norm_in[node];
    const float4 b24 = reinterpret_cast<const float4*>(b2)[q];
    float4 o;
    o.x = acc.x * ni + b24.x;
    o.y = acc.y * ni + b24.y;
    o.z = acc.z * ni + b24.z;
    o.w = acc.w * ni + b24.w;
    reinterpret_cast<float4*>(out)[(size_t)node * 8 + q] = o;
}

// ---------------- launch ----------------

static inline size_t align256(size_t x) { return (x + 255) & ~(size_t)255; }

extern "C" void kernel_launch(void* const* d_in, const int* in_sizes, int n_in,
                              void* d_out, int out_size, void* d_ws, size_t ws_size,
                              hipStream_t stream) {
    const float* features = (const float*)d_in[0];
    const float* W1 = (const float*)d_in[1];
    const float* b1 = (const float*)d_in[2];
    const float* W2 = (const float*)d_in[3];
    const float* b2 = (const float*)d_in[4];
    const int* src = (const int*)d_in[5];
    const int* dst = (const int*)d_in[6];
    const int E = in_sizes[5];
    const int n = N_NODES;
    float* out = (float*)d_out;

    char* ws = (char*)d_ws;
    size_t off = 0;
    float* norm_out = (float*)(ws + off); off += align256((size_t)n * 4);
    float* norm_in = (float*)(ws + off);  off += align256((size_t)n * 4);
    int* row_ptr = (int*)(ws + off);      off += align256((size_t)n * 4);
    int* deg_arr = (int*)(ws + off);      off += align256((size_t)n * 4);
    unsigned* startD = (unsigned*)(ws + off); off += align256((NBUCK + 1) * 4);
    unsigned* startS = (unsigned*)(ws + off); off += align256((NBUCK + 1) * 4);
    unsigned* totD = (unsigned*)(ws + off);   off += align256(NBUCK * 4);
    unsigned* totS = (unsigned*)(ws + off);   off += align256(NBUCK * 4);
    int* col = (int*)(ws + off);              off += align256((size_t)E * 4);  // 6.4 MB

    // region X: pairD+valS (live: part_scatter -> bucket kernels) then h2h (live: agg1 -> agg2)
    size_t regX = off;
    unsigned* pairD = (unsigned*)(ws + regX);                        // 6.4 MB
    unsigned* valS = (unsigned*)(ws + regX + (size_t)E * 4);         // 6.4 MB
    float2* h2h = (float2*)(ws + regX);                              // 6.4 MB (fp16 packed)
    off += align256((size_t)2 * E * 4);
    // region Y: cntD+cntS (live: part_count -> part_scatter) then h1h (live: gemm1 -> agg1)
    size_t regY = off;
    unsigned* cntD = (unsigned*)(ws + regY);                         // 100 KB
    unsigned* cntS = (unsigned*)(ws + regY + (size_t)NBLK * NBUCK * 4);
    float2* h1h = (float2*)(ws + regY);                              // 6.4 MB (fp16 packed)

    // phase A: partition edges by dst-bucket (pairs) and src-bucket (locals)
    part_count<<<NBLK, PART_THREADS, 0, stream>>>(src, dst, E, cntD, cntS);
    col_scan<<<NBUCK, NBLK, 0, stream>>>(cntD, totD);
    col_scan<<<NBUCK, NBLK, 0, stream>>>(cntS, totS);
    total_scan<<<1, 1024, 0, stream>>>(totD, startD);
    total_scan<<<1, 1024, 0, stream>>>(totS, startS);
    part_scatter<<<NBLK, PART_THREADS, 0, stream>>>(src, dst, E, cntD, cntS, startD, startS,
                                                    pairD, valS);

    // phase B: per-bucket counting sort -> CSR (+ norm_in), src norms
    bucket_sort<<<NBUCK, 256, 0, stream>>>(pairD, startD, col, row_ptr, deg_arr, norm_in, n);
    bucket_norms_src<<<NBUCK, 256, 0, stream>>>(valS, startS, norm_out, n);

    // layer 1 projection (+ norm_out prescale), fp16 output
    gemm1_kernel<<<(n + G1_NODES - 1) / G1_NODES, G1_BLOCK, 0, stream>>>(features, W1, norm_out,
                                                                         h1h, n);

    // gather aggregation (8 lanes/node, fp16 tables), fused epilogues
    agg1_kernel<<<(n + 31) / 32, 256, 0, stream>>>(h1h, row_ptr, deg_arr, col, norm_in,
                                                   norm_out, b1, W2, h2h, n);
    agg2_kernel<<<(n + 31) / 32, 256, 0, stream>>>(h2h, row_ptr, deg_arr, col, norm_in, b2, out, n);
}

// Round 15
// 133.165 us; speedup vs baseline: 1.5751x; 1.1899x over previous
//
#include <hip/hip_runtime.h>
#include <hip/hip_fp16.h>

#define N_NODES 100000
#define F_IN 128
#define F_HID 32
#define BN 512                  // nodes per bucket (pow2)
#define NBUCK 196               // ceil(100000/512)
#define NBLK 128                // edge partition chunks
#define PART_THREADS 1024

typedef _Float16 f16x8 __attribute__((ext_vector_type(8)));
typedef float f32x4 __attribute__((ext_vector_type(4)));

// ---------------- phase A: bucket partition of edges (no global atomics) ----------------

__global__ __launch_bounds__(PART_THREADS) void part_count(const int* __restrict__ src,
                                                           const int* __restrict__ dst, int E,
                                                           unsigned* __restrict__ cntD,
                                                           unsigned* __restrict__ cntS) {
    __shared__ unsigned cd[NBUCK], cs[NBUCK];
    for (int i = threadIdx.x; i < NBUCK; i += PART_THREADS) { cd[i] = 0; cs[i] = 0; }
    __syncthreads();
    int chunk = (E + NBLK - 1) / NBLK;
    int e0 = blockIdx.x * chunk, e1 = min(E, e0 + chunk);
    for (int e = e0 + threadIdx.x; e < e1; e += PART_THREADS) {
        atomicAdd(&cd[((unsigned)dst[e]) >> 9], 1u);   // LDS atomic
        atomicAdd(&cs[((unsigned)src[e]) >> 9], 1u);
    }
    __syncthreads();
    unsigned* od = cntD + (size_t)blockIdx.x * NBUCK;
    unsigned* os = cntS + (size_t)blockIdx.x * NBUCK;
    for (int i = threadIdx.x; i < NBUCK; i += PART_THREADS) { od[i] = cd[i]; os[i] = cs[i]; }
}

// per-bucket exclusive scan over blocks, D and S fused: blockIdx < NBUCK -> D, else S
__global__ __launch_bounds__(NBLK) void col_scan2(unsigned* __restrict__ cntD,
                                                  unsigned* __restrict__ cntS,
                                                  unsigned* __restrict__ totD,
                                                  unsigned* __restrict__ totS) {
    __shared__ unsigned buf[2][NBLK];
    bool isD = blockIdx.x < NBUCK;
    unsigned* cnt = isD ? cntD : cntS;
    unsigned* totals = isD ? totD : totS;
    int k = isD ? blockIdx.x : blockIdx.x - NBUCK;
    int t = threadIdx.x;
    unsigned v = cnt[(size_t)t * NBUCK + k];
    buf[0][t] = v;
    __syncthreads();
    int cur = 0;
    for (int off = 1; off < NBLK; off <<= 1) {
        unsigned x = buf[cur][t];
        if (t >= off) x += buf[cur][t - off];
        buf[cur ^ 1][t] = x;
        cur ^= 1;
        __syncthreads();
    }
    cnt[(size_t)t * NBUCK + k] = buf[cur][t] - v;  // exclusive over blocks
    if (t == NBLK - 1) totals[k] = buf[cur][NBLK - 1];
}

// exclusive scan of bucket totals, D and S fused: block 0 -> D, block 1 -> S
__global__ __launch_bounds__(1024) void total_scan2(const unsigned* __restrict__ totD,
                                                    const unsigned* __restrict__ totS,
                                                    unsigned* __restrict__ startD,
                                                    unsigned* __restrict__ startS) {
    __shared__ unsigned buf[2][1024];
    const unsigned* totals = (blockIdx.x == 0) ? totD : totS;
    unsigned* start = (blockIdx.x == 0) ? startD : startS;
    int t = threadIdx.x;
    buf[0][t] = (t < NBUCK) ? totals[t] : 0;
    __syncthreads();
    int cur = 0;
    for (int off = 1; off < 1024; off <<= 1) {
        unsigned x = buf[cur][t];
        if (t >= off) x += buf[cur][t - off];
        buf[cur ^ 1][t] = x;
        cur ^= 1;
        __syncthreads();
    }
    if (t < NBUCK) start[t + 1] = buf[cur][t];
    if (t == 0) start[0] = 0;
}

// scatter edges into bucket-partitioned layout; slots disjoint by construction
__global__ __launch_bounds__(PART_THREADS) void part_scatter(const int* __restrict__ src,
                                                             const int* __restrict__ dst, int E,
                                                             const unsigned* __restrict__ cntD,
                                                             const unsigned* __restrict__ cntS,
                                                             const unsigned* __restrict__ startD,
                                                             const unsigned* __restrict__ startS,
                                                             unsigned* __restrict__ pairD,
                                                             unsigned short* __restrict__ valS) {
    __shared__ unsigned curD[NBUCK], curS[NBUCK];
    for (int i = threadIdx.x; i < NBUCK; i += PART_THREADS) { curD[i] = 0; curS[i] = 0; }
    __syncthreads();
    int chunk = (E + NBLK - 1) / NBLK;
    int e0 = blockIdx.x * chunk, e1 = min(E, e0 + chunk);
    const unsigned* bd = cntD + (size_t)blockIdx.x * NBUCK;
    const unsigned* bs = cntS + (size_t)blockIdx.x * NBUCK;
    for (int e = e0 + threadIdx.x; e < e1; e += PART_THREADS) {
        unsigned s = (unsigned)src[e], d = (unsigned)dst[e];
        unsigned kd = d >> 9, ks = s >> 9;
        unsigned rd = atomicAdd(&curD[kd], 1u);                 // LDS rank
        pairD[startD[kd] + bd[kd] + rd] = s | ((d & 511u) << 17);
        unsigned rs = atomicAdd(&curS[ks], 1u);
        valS[startS[ks] + bs[ks] + rs] = (unsigned short)(s & 511u);
    }
}

// ---------------- phase B fused: counting sort -> CSR (blocks 0..195) + src norms (196..391) ----

__global__ __launch_bounds__(256) void sort_norms(const unsigned* __restrict__ pairD,
                                                  const unsigned* __restrict__ startD,
                                                  const unsigned short* __restrict__ valS,
                                                  const unsigned* __restrict__ startS,
                                                  int* __restrict__ col, int* __restrict__ row_ptr,
                                                  int* __restrict__ deg_arr,
                                                  float* __restrict__ norm_in,
                                                  float* __restrict__ norm_out, int n) {
    __shared__ unsigned cnt[BN];
    __shared__ unsigned base[BN];
    __shared__ unsigned sbuf[2][BN];
    int t = threadIdx.x;
    if (blockIdx.x < NBUCK) {
        int k = blockIdx.x;
        cnt[t] = 0; cnt[t + 256] = 0;
        __syncthreads();
        unsigned a0 = startD[k], a1 = startD[k + 1];
        for (unsigned i = a0 + t; i < a1; i += 256)
            atomicAdd(&cnt[(pairD[i] >> 17) & (BN - 1)], 1u);
        __syncthreads();
        unsigned v0 = cnt[t], v1 = cnt[t + 256];
        sbuf[0][t] = v0; sbuf[0][t + 256] = v1;
        __syncthreads();
        int cur = 0;
        for (int off = 1; off < BN; off <<= 1) {
            unsigned x0 = sbuf[cur][t];
            if (t >= off) x0 += sbuf[cur][t - off];
            unsigned x1 = sbuf[cur][t + 256] + sbuf[cur][t + 256 - off];
            sbuf[cur ^ 1][t] = x0;
            sbuf[cur ^ 1][t + 256] = x1;
            cur ^= 1;
            __syncthreads();
        }
        base[t] = a0 + sbuf[cur][t] - v0;
        base[t + 256] = a0 + sbuf[cur][t + 256] - v1;
        int node0 = k * BN + t, node1 = k * BN + t + 256;
        if (node0 < n) {
            row_ptr[node0] = (int)base[t];
            deg_arr[node0] = (int)v0;
            norm_in[node0] = rsqrtf((float)(v0 > 1u ? v0 : 1u));
        }
        if (node1 < n) {
            row_ptr[node1] = (int)base[t + 256];
            deg_arr[node1] = (int)v1;
            norm_in[node1] = rsqrtf((float)(v1 > 1u ? v1 : 1u));
        }
        cnt[t] = 0; cnt[t + 256] = 0;
        __syncthreads();
        for (unsigned i = a0 + t; i < a1; i += 256) {
            unsigned pv = pairD[i];
            unsigned l = (pv >> 17) & (BN - 1);
            unsigned r = atomicAdd(&cnt[l], 1u);   // LDS rank
            col[base[l] + r] = (int)(pv & 0x1FFFFu);
        }
    } else {
        int k = blockIdx.x - NBUCK;
        cnt[t] = 0; cnt[t + 256] = 0;
        __syncthreads();
        unsigned a0 = startS[k], a1 = startS[k + 1];
        for (unsigned i = a0 + t; i < a1; i += 256)
            atomicAdd(&cnt[valS[i]], 1u);
        __syncthreads();
#pragma unroll
        for (int h = 0; h < 2; ++h) {
            int l = t + h * 256;
            int node = k * BN + l;
            if (node < n) {
                unsigned c = cnt[l];
                norm_out[node] = rsqrtf((float)(c > 1u ? c : 1u));
            }
        }
    }
}

// ---------------- fp16 pack/unpack helpers ----------------

__device__ __forceinline__ float2 pack_half4(float a, float b, float c, float d) {
    __half2 h0 = __floats2half2_rn(a, b);
    __half2 h1 = __floats2half2_rn(c, d);
    float2 r;
    r.x = *reinterpret_cast<float*>(&h0);
    r.y = *reinterpret_cast<float*>(&h1);
    return r;
}

__device__ __forceinline__ void unpack_half4(float2 v, float4& acc) {
    __half2 ha = *reinterpret_cast<__half2*>(&v.x);
    __half2 hb = *reinterpret_cast<__half2*>(&v.y);
    float2 fa = __half22float2(ha);
    float2 fb = __half22float2(hb);
    acc.x += fa.x; acc.y += fa.y; acc.z += fb.x; acc.w += fb.y;
}

// ---------------- layer-1 projection via MFMA: h1 = (x @ W1) * norm_out, fp16 out ----------
// D = A·B with A = W1^T tile (16 feat x 32 k), B = x^T tile (32 k x 16 nodes).
// k-mapping (elems 0-3: k=kg*4+j, elems 4-7: k=16+kg*4+j) is identical for A and B, so any
// HW k-permutation cancels in the dot product. C/D: col=lane&15(node), row=(lane>>4)*4+i
// (HW-verified, dtype-independent). One wave = 16 nodes; memory-bound on x (51.2 MB).

__global__ __launch_bounds__(256) void gemm1_mfma(const float* __restrict__ x,
                                                  const float* __restrict__ W,
                                                  const float* __restrict__ norm_out,
                                                  float2* __restrict__ hh, int n) {
    int lane = threadIdx.x & 63;
    int wv = threadIdx.x >> 6;
    int node0 = blockIdx.x * 64 + wv * 16;
    int m = lane & 15;
    int kg = lane >> 4;            // 0..3
    int node = node0 + m;
    int nodeClamp = node < n ? node : (n - 1);
    const float* xrow = x + (size_t)nodeClamp * F_IN;

    // B fragments from x row (fp32 -> fp16 in-register)
    f16x8 bfrag[4];
#pragma unroll
    for (int c = 0; c < 4; ++c) {
        float4 lo = *reinterpret_cast<const float4*>(xrow + c * 32 + kg * 4);
        float4 hi = *reinterpret_cast<const float4*>(xrow + c * 32 + 16 + kg * 4);
        f16x8 b;
        b[0] = (_Float16)lo.x; b[1] = (_Float16)lo.y; b[2] = (_Float16)lo.z; b[3] = (_Float16)lo.w;
        b[4] = (_Float16)hi.x; b[5] = (_Float16)hi.y; b[6] = (_Float16)hi.z; b[7] = (_Float16)hi.w;
        bfrag[c] = b;
    }
    f32x4 acc0 = {0.f, 0.f, 0.f, 0.f};
    f32x4 acc1 = {0.f, 0.f, 0.f, 0.f};
#pragma unroll
    for (int c = 0; c < 4; ++c) {
        f16x8 a0, a1;
#pragma unroll
        for (int j = 0; j < 4; ++j) {
            int k0 = c * 32 + kg * 4 + j;
            int k1 = k0 + 16;
            a0[j]     = (_Float16)W[k0 * F_HID + m];
            a0[j + 4] = (_Float16)W[k1 * F_HID + m];
            a1[j]     = (_Float16)W[k0 * F_HID + 16 + m];
            a1[j + 4] = (_Float16)W[k1 * F_HID + 16 + m];
        }
        acc0 = __builtin_amdgcn_mfma_f32_16x16x32_f16(a0, bfrag[c], acc0, 0, 0, 0);
        acc1 = __builtin_amdgcn_mfma_f32_16x16x32_f16(a1, bfrag[c], acc1, 0, 0, 0);
    }
    if (node < n) {
        float no = norm_out[node];
        hh[(size_t)node * 8 + kg] = pack_half4(acc0[0] * no, acc0[1] * no, acc0[2] * no, acc0[3] * no);
        hh[(size_t)node * 8 + 4 + kg] = pack_half4(acc1[0] * no, acc1[1] * no, acc1[2] * no, acc1[3] * no);
    }
}

// ---------------- gather aggregation: 8 lanes/node, fp16 half4/lane, 8-edge unroll ----------

__device__ __forceinline__ float4 shfl4_8(float4 v, int sl) {
    float4 r;
    r.x = __shfl(v.x, sl, 8);
    r.y = __shfl(v.y, sl, 8);
    r.z = __shfl(v.z, sl, 8);
    r.w = __shfl(v.w, sl, 8);
    return r;
}

// layer 1: agg + norm_in + b1 + relu, GEMM2 (8-lane shfl), prescale norm_out -> h2h (fp16)
__global__ __launch_bounds__(256) void agg1_kernel(const float2* __restrict__ h1h,
                                                   const int* __restrict__ row_ptr,
                                                   const int* __restrict__ deg_arr,
                                                   const int* __restrict__ col,
                                                   const float* __restrict__ norm_in,
                                                   const float* __restrict__ norm_out,
                                                   const float* __restrict__ b1,
                                                   const float* __restrict__ W2,
                                                   float2* __restrict__ h2h, int n) {
    __shared__ float W2l[F_HID * F_HID];  // row k holds W2[k][0..31]
    for (int i = threadIdx.x; i < F_HID * F_HID; i += 256) W2l[i] = W2[i];
    __syncthreads();
    const float4* W24 = reinterpret_cast<const float4*>(W2l);
    int q = threadIdx.x & 7;                 // lane in 8-lane group
    int node = blockIdx.x * 32 + (threadIdx.x >> 3);
    if (node >= n) return;
    int start = row_ptr[node];
    int deg = deg_arr[node];
    float4 acc = make_float4(0.f, 0.f, 0.f, 0.f);
    int jj = 0;
    for (; jj + 8 <= deg; jj += 8) {
        int c = col[start + jj + q];         // 8 lanes: one coalesced 32B load
#pragma unroll
        for (int m = 0; m < 8; ++m) {
            int s = __shfl(c, m, 8);
            float2 v = h1h[(size_t)s * 8 + q];
            unpack_half4(v, acc);
        }
    }
    int rem = deg - jj;
    if (rem > 0) {
        int c = col[start + jj + (q < rem ? q : 0)];
        for (int m = 0; m < rem; ++m) {
            int s = __shfl(c, m, 8);
            float2 v = h1h[(size_t)s * 8 + q];
            unpack_half4(v, acc);
        }
    }
    float ni = norm_in[node];
    const float4 b14 = reinterpret_cast<const float4*>(b1)[q];
    float4 t;
    t.x = fmaxf(acc.x * ni + b14.x, 0.f);
    t.y = fmaxf(acc.y * ni + b14.y, 0.f);
    t.z = fmaxf(acc.z * ni + b14.z, 0.f);
    t.w = fmaxf(acc.w * ni + b14.w, 0.f);
    // GEMM2: o[f] = sum_k t[k] * W2[k][f]; t distributed 4-per-lane over 8 lanes
    float4 o = make_float4(0.f, 0.f, 0.f, 0.f);
#pragma unroll
    for (int sl = 0; sl < 8; ++sl) {
        float4 tt = shfl4_8(t, sl);
        int kb = sl * 4;
        float4 w0 = W24[(kb + 0) * 8 + q];
        float4 w1 = W24[(kb + 1) * 8 + q];
        float4 w2 = W24[(kb + 2) * 8 + q];
        float4 w3 = W24[(kb + 3) * 8 + q];
        o.x += tt.x * w0.x + tt.y * w1.x + tt.z * w2.x + tt.w * w3.x;
        o.y += tt.x * w0.y + tt.y * w1.y + tt.z * w2.y + tt.w * w3.y;
        o.z += tt.x * w0.z + tt.y * w1.z + tt.z * w2.z + tt.w * w3.z;
        o.w += tt.x * w0.w + tt.y * w1.w + tt.z * w2.w + tt.w * w3.w;
    }
    float no = norm_out[node];
    h2h[(size_t)node * 8 + q] = pack_half4(o.x * no, o.y * no, o.z * no, o.w * no);
}

// layer 2: agg + norm_in + b2 -> out (fp32)
__global__ __launch_bounds__(256) void agg2_kernel(const float2* __restrict__ h2h,
                                                   const int* __restrict__ row_ptr,
                                                   const int* __restrict__ deg_arr,
                                                   const int* __restrict__ col,
                                                   const float* __restrict__ norm_in,
                                                   const float* __restrict__ b2,
                                                   float* __restrict__ out, int n) {
    int q = threadIdx.x & 7;
    int node = blockIdx.x * 32 + (threadIdx.x >> 3);
    if (node >= n) return;
    int start = row_ptr[node];
    int deg = deg_arr[node];
    float4 acc = make_float4(0.f, 0.f, 0.f, 0.f);
    int jj = 0;
    for (; jj + 8 <= deg; jj += 8) {
        int c = col[start + jj + q];
#pragma unroll
        for (int m = 0; m < 8; ++m) {
            int s = __shfl(c, m, 8);
            float2 v = h2h[(size_t)s * 8 + q];
            unpack_half4(v, acc);
        }
    }
    int rem = deg - jj;
    if (rem > 0) {
        int c = col[start + jj + (q < rem ? q : 0)];
        for (int m = 0; m < rem; ++m) {
            int s = __shfl(c, m, 8);
            float2 v = h2h[(size_t)s * 8 + q];
            unpack_half4(v, acc);
        }
    }
    float ni = norm_in[node];
    const float4 b24 = reinterpret_cast<const float4*>(b2)[q];
    float4 o;
    o.x = acc.x * ni + b24.x;
    o.y = acc.y * ni + b24.y;
    o.z = acc.z * ni + b24.z;
    o.w = acc.w * ni + b24.w;
    reinterpret_cast<float4*>(out)[(size_t)node * 8 + q] = o;
}

// ---------------- launch ----------------

static inline size_t align256(size_t x) { return (x + 255) & ~(size_t)255; }

extern "C" void kernel_launch(void* const* d_in, const int* in_sizes, int n_in,
                              void* d_out, int out_size, void* d_ws, size_t ws_size,
                              hipStream_t stream) {
    const float* features = (const float*)d_in[0];
    const float* W1 = (const float*)d_in[1];
    const float* b1 = (const float*)d_in[2];
    const float* W2 = (const float*)d_in[3];
    const float* b2 = (const float*)d_in[4];
    const int* src = (const int*)d_in[5];
    const int* dst = (const int*)d_in[6];
    const int E = in_sizes[5];
    const int n = N_NODES;
    float* out = (float*)d_out;

    char* ws = (char*)d_ws;
    size_t off = 0;
    float* norm_out = (float*)(ws + off); off += align256((size_t)n * 4);
    float* norm_in = (float*)(ws + off);  off += align256((size_t)n * 4);
    int* row_ptr = (int*)(ws + off);      off += align256((size_t)n * 4);
    int* deg_arr = (int*)(ws + off);      off += align256((size_t)n * 4);
    unsigned* startD = (unsigned*)(ws + off); off += align256((NBUCK + 1) * 4);
    unsigned* startS = (unsigned*)(ws + off); off += align256((NBUCK + 1) * 4);
    unsigned* totD = (unsigned*)(ws + off);   off += align256(NBUCK * 4);
    unsigned* totS = (unsigned*)(ws + off);   off += align256(NBUCK * 4);
    int* col = (int*)(ws + off);              off += align256((size_t)E * 4);  // 6.4 MB

    // region X: pairD+valS (live: part_scatter -> sort_norms) then h2h (live: agg1 -> agg2)
    size_t regX = off;
    unsigned* pairD = (unsigned*)(ws + regX);                        // 6.4 MB
    unsigned short* valS = (unsigned short*)(ws + regX + (size_t)E * 4);  // 3.2 MB (u16)
    float2* h2h = (float2*)(ws + regX);                              // 6.4 MB (fp16 packed)
    off += align256((size_t)2 * E * 4);
    // region Y: cntD+cntS (live: part_count -> part_scatter) then h1h (live: gemm1 -> agg1)
    size_t regY = off;
    unsigned* cntD = (unsigned*)(ws + regY);                         // 100 KB
    unsigned* cntS = (unsigned*)(ws + regY + (size_t)NBLK * NBUCK * 4);
    float2* h1h = (float2*)(ws + regY);                              // 6.4 MB (fp16 packed)

    // phase A: partition edges by dst-bucket (pairs) and src-bucket (u16 locals)
    part_count<<<NBLK, PART_THREADS, 0, stream>>>(src, dst, E, cntD, cntS);
    col_scan2<<<2 * NBUCK, NBLK, 0, stream>>>(cntD, cntS, totD, totS);
    total_scan2<<<2, 1024, 0, stream>>>(totD, totS, startD, startS);
    part_scatter<<<NBLK, PART_THREADS, 0, stream>>>(src, dst, E, cntD, cntS, startD, startS,
                                                    pairD, valS);

    // phase B fused: counting sort -> CSR (+ norm_in) | src norms
    sort_norms<<<2 * NBUCK, 256, 0, stream>>>(pairD, startD, valS, startS, col, row_ptr,
                                              deg_arr, norm_in, norm_out, n);

    // layer 1 projection via MFMA (+ norm_out prescale), fp16 output
    gemm1_mfma<<<(n + 63) / 64, 256, 0, stream>>>(features, W1, norm_out, h1h, n);

    // gather aggregation (8 lanes/node, fp16 tables), fused epilogues
    agg1_kernel<<<(n + 31) / 32, 256, 0, stream>>>(h1h, row_ptr, deg_arr, col, norm_in,
                                                   norm_out, b1, W2, h2h, n);
    agg2_kernel<<<(n + 31) / 32, 256, 0, stream>>>(h2h, row_ptr, deg_arr, col, norm_in, b2, out, n);
}

// Round 16
// 115.162 us; speedup vs baseline: 1.8214x; 1.1563x over previous
//
#include <hip/hip_runtime.h>
#include <hip/hip_fp16.h>

#define N_NODES 100000
#define F_IN 128
#define F_HID 32
#define BN 512                  // nodes per bucket (pow2)
#define NBUCK 196               // ceil(100000/512)
#define NBLK 256                // edge partition chunks (full device at 1024 thr)
#define PART_THREADS 1024
#define STAGE_CAP 12288         // staged edges per bucket (48 KB); avg 8192, 6-sigma ~8700

typedef _Float16 f16x8 __attribute__((ext_vector_type(8)));
typedef float f32x4 __attribute__((ext_vector_type(4)));

// ---------------- phase A: bucket partition of edges (no global atomics) ----------------

__global__ __launch_bounds__(PART_THREADS) void part_count(const int* __restrict__ src,
                                                           const int* __restrict__ dst, int E,
                                                           unsigned* __restrict__ cntD,
                                                           unsigned* __restrict__ cntS) {
    __shared__ unsigned cd[NBUCK], cs[NBUCK];
    for (int i = threadIdx.x; i < NBUCK; i += PART_THREADS) { cd[i] = 0; cs[i] = 0; }
    __syncthreads();
    int chunk = (E + NBLK - 1) / NBLK;
    int e0 = blockIdx.x * chunk, e1 = min(E, e0 + chunk);
    for (int e = e0 + threadIdx.x; e < e1; e += PART_THREADS) {
        atomicAdd(&cd[((unsigned)dst[e]) >> 9], 1u);   // LDS atomic
        atomicAdd(&cs[((unsigned)src[e]) >> 9], 1u);
    }
    __syncthreads();
    unsigned* od = cntD + (size_t)blockIdx.x * NBUCK;
    unsigned* os = cntS + (size_t)blockIdx.x * NBUCK;
    for (int i = threadIdx.x; i < NBUCK; i += PART_THREADS) { od[i] = cd[i]; os[i] = cs[i]; }
}

// per-bucket exclusive scan over blocks, D and S fused: blockIdx < NBUCK -> D, else S
__global__ __launch_bounds__(NBLK) void col_scan2(unsigned* __restrict__ cntD,
                                                  unsigned* __restrict__ cntS,
                                                  unsigned* __restrict__ totD,
                                                  unsigned* __restrict__ totS) {
    __shared__ unsigned buf[2][NBLK];
    bool isD = blockIdx.x < NBUCK;
    unsigned* cnt = isD ? cntD : cntS;
    unsigned* totals = isD ? totD : totS;
    int k = isD ? blockIdx.x : blockIdx.x - NBUCK;
    int t = threadIdx.x;
    unsigned v = cnt[(size_t)t * NBUCK + k];
    buf[0][t] = v;
    __syncthreads();
    int cur = 0;
    for (int off = 1; off < NBLK; off <<= 1) {
        unsigned x = buf[cur][t];
        if (t >= off) x += buf[cur][t - off];
        buf[cur ^ 1][t] = x;
        cur ^= 1;
        __syncthreads();
    }
    cnt[(size_t)t * NBUCK + k] = buf[cur][t] - v;  // exclusive over blocks
    if (t == NBLK - 1) totals[k] = buf[cur][NBLK - 1];
}

// exclusive scan of bucket totals, D and S fused: block 0 -> D, block 1 -> S
__global__ __launch_bounds__(1024) void total_scan2(const unsigned* __restrict__ totD,
                                                    const unsigned* __restrict__ totS,
                                                    unsigned* __restrict__ startD,
                                                    unsigned* __restrict__ startS) {
    __shared__ unsigned buf[2][1024];
    const unsigned* totals = (blockIdx.x == 0) ? totD : totS;
    unsigned* start = (blockIdx.x == 0) ? startD : startS;
    int t = threadIdx.x;
    buf[0][t] = (t < NBUCK) ? totals[t] : 0;
    __syncthreads();
    int cur = 0;
    for (int off = 1; off < 1024; off <<= 1) {
        unsigned x = buf[cur][t];
        if (t >= off) x += buf[cur][t - off];
        buf[cur ^ 1][t] = x;
        cur ^= 1;
        __syncthreads();
    }
    if (t < NBUCK) start[t + 1] = buf[cur][t];
    if (t == 0) start[0] = 0;
}

// scatter edges into bucket-partitioned layout; slots disjoint by construction
__global__ __launch_bounds__(PART_THREADS) void part_scatter(const int* __restrict__ src,
                                                             const int* __restrict__ dst, int E,
                                                             const unsigned* __restrict__ cntD,
                                                             const unsigned* __restrict__ cntS,
                                                             const unsigned* __restrict__ startD,
                                                             const unsigned* __restrict__ startS,
                                                             unsigned* __restrict__ pairD,
                                                             unsigned short* __restrict__ valS) {
    __shared__ unsigned curD[NBUCK], curS[NBUCK];
    for (int i = threadIdx.x; i < NBUCK; i += PART_THREADS) { curD[i] = 0; curS[i] = 0; }
    __syncthreads();
    int chunk = (E + NBLK - 1) / NBLK;
    int e0 = blockIdx.x * chunk, e1 = min(E, e0 + chunk);
    const unsigned* bd = cntD + (size_t)blockIdx.x * NBUCK;
    const unsigned* bs = cntS + (size_t)blockIdx.x * NBUCK;
    for (int e = e0 + threadIdx.x; e < e1; e += PART_THREADS) {
        unsigned s = (unsigned)src[e], d = (unsigned)dst[e];
        unsigned kd = d >> 9, ks = s >> 9;
        unsigned rd = atomicAdd(&curD[kd], 1u);                 // LDS rank
        pairD[startD[kd] + bd[kd] + rd] = s | ((d & 511u) << 17);
        unsigned rs = atomicAdd(&curS[ks], 1u);
        valS[startS[ks] + bs[ks] + rs] = (unsigned short)(s & 511u);
    }
}

// ---------------- phase B fused: LDS-staged counting sort -> CSR | src norms ----------------

__global__ __launch_bounds__(512) void sort_norms(const unsigned* __restrict__ pairD,
                                                  const unsigned* __restrict__ startD,
                                                  const unsigned short* __restrict__ valS,
                                                  const unsigned* __restrict__ startS,
                                                  int* __restrict__ col, int* __restrict__ row_ptr,
                                                  int* __restrict__ deg_arr,
                                                  float* __restrict__ norm_in,
                                                  float* __restrict__ norm_out, int n) {
    __shared__ unsigned ed[STAGE_CAP];    // 48 KB edge stage
    __shared__ unsigned cnt[BN];
    __shared__ unsigned base[BN];
    __shared__ unsigned sbuf[2][BN];
    int t = threadIdx.x;   // 0..511
    if (blockIdx.x < NBUCK) {
        int k = blockIdx.x;
        unsigned a0 = startD[k], a1 = startD[k + 1];
        int tot = (int)(a1 - a0);
        int staged = tot < STAGE_CAP ? tot : STAGE_CAP;
        for (int i = t; i < staged; i += 512) ed[i] = pairD[a0 + i];  // one coalesced read
        cnt[t] = 0;
        __syncthreads();
        for (int i = t; i < staged; i += 512)
            atomicAdd(&cnt[(ed[i] >> 17) & (BN - 1)], 1u);
        for (int i = staged + t; i < tot; i += 512)                   // overflow fallback
            atomicAdd(&cnt[(pairD[a0 + i] >> 17) & (BN - 1)], 1u);
        __syncthreads();
        unsigned v = cnt[t];
        sbuf[0][t] = v;
        __syncthreads();
        int cur = 0;
        for (int off = 1; off < BN; off <<= 1) {
            unsigned x = sbuf[cur][t];
            if (t >= off) x += sbuf[cur][t - off];
            sbuf[cur ^ 1][t] = x;
            cur ^= 1;
            __syncthreads();
        }
        base[t] = a0 + sbuf[cur][t] - v;  // exclusive within bucket
        int node = k * BN + t;
        if (node < n) {
            row_ptr[node] = (int)base[t];
            deg_arr[node] = (int)v;
            norm_in[node] = rsqrtf((float)(v > 1u ? v : 1u));
        }
        cnt[t] = 0;  // reuse as cursor
        __syncthreads();
        for (int i = t; i < staged; i += 512) {
            unsigned pv = ed[i];
            unsigned l = (pv >> 17) & (BN - 1);
            unsigned r = atomicAdd(&cnt[l], 1u);   // LDS rank
            col[base[l] + r] = (int)(pv & 0x1FFFFu);
        }
        for (int i = staged + t; i < tot; i += 512) {
            unsigned pv = pairD[a0 + i];
            unsigned l = (pv >> 17) & (BN - 1);
            unsigned r = atomicAdd(&cnt[l], 1u);
            col[base[l] + r] = (int)(pv & 0x1FFFFu);
        }
    } else {
        int k = blockIdx.x - NBUCK;
        cnt[t] = 0;
        __syncthreads();
        unsigned a0 = startS[k], a1 = startS[k + 1];
        for (unsigned i = a0 + t; i < a1; i += 512)
            atomicAdd(&cnt[valS[i]], 1u);
        __syncthreads();
        int node = k * BN + t;
        if (node < n) {
            unsigned c = cnt[t];
            norm_out[node] = rsqrtf((float)(c > 1u ? c : 1u));
        }
    }
}

// ---------------- fp16 pack/unpack helpers ----------------

__device__ __forceinline__ float2 pack_half4(float a, float b, float c, float d) {
    __half2 h0 = __floats2half2_rn(a, b);
    __half2 h1 = __floats2half2_rn(c, d);
    float2 r;
    r.x = *reinterpret_cast<float*>(&h0);
    r.y = *reinterpret_cast<float*>(&h1);
    return r;
}

__device__ __forceinline__ void unpack_half4(float2 v, float4& acc) {
    __half2 ha = *reinterpret_cast<__half2*>(&v.x);
    __half2 hb = *reinterpret_cast<__half2*>(&v.y);
    float2 fa = __half22float2(ha);
    float2 fb = __half22float2(hb);
    acc.x += fa.x; acc.y += fa.y; acc.z += fb.x; acc.w += fb.y;
}

// ---------------- layer-1 projection via MFMA: h1 = (x @ W1) * norm_out, fp16 out ----------

__global__ __launch_bounds__(256) void gemm1_mfma(const float* __restrict__ x,
                                                  const float* __restrict__ W,
                                                  const float* __restrict__ norm_out,
                                                  float2* __restrict__ hh, int n) {
    int lane = threadIdx.x & 63;
    int wv = threadIdx.x >> 6;
    int node0 = blockIdx.x * 64 + wv * 16;
    int m = lane & 15;
    int kg = lane >> 4;            // 0..3
    int node = node0 + m;
    int nodeClamp = node < n ? node : (n - 1);
    const float* xrow = x + (size_t)nodeClamp * F_IN;

    // B fragments from x row (fp32 -> fp16 in-register)
    f16x8 bfrag[4];
#pragma unroll
    for (int c = 0; c < 4; ++c) {
        float4 lo = *reinterpret_cast<const float4*>(xrow + c * 32 + kg * 4);
        float4 hi = *reinterpret_cast<const float4*>(xrow + c * 32 + 16 + kg * 4);
        f16x8 b;
        b[0] = (_Float16)lo.x; b[1] = (_Float16)lo.y; b[2] = (_Float16)lo.z; b[3] = (_Float16)lo.w;
        b[4] = (_Float16)hi.x; b[5] = (_Float16)hi.y; b[6] = (_Float16)hi.z; b[7] = (_Float16)hi.w;
        bfrag[c] = b;
    }
    f32x4 acc0 = {0.f, 0.f, 0.f, 0.f};
    f32x4 acc1 = {0.f, 0.f, 0.f, 0.f};
#pragma unroll
    for (int c = 0; c < 4; ++c) {
        f16x8 a0, a1;
#pragma unroll
        for (int j = 0; j < 4; ++j) {
            int k0 = c * 32 + kg * 4 + j;
            int k1 = k0 + 16;
            a0[j]     = (_Float16)W[k0 * F_HID + m];
            a0[j + 4] = (_Float16)W[k1 * F_HID + m];
            a1[j]     = (_Float16)W[k0 * F_HID + 16 + m];
            a1[j + 4] = (_Float16)W[k1 * F_HID + 16 + m];
        }
        acc0 = __builtin_amdgcn_mfma_f32_16x16x32_f16(a0, bfrag[c], acc0, 0, 0, 0);
        acc1 = __builtin_amdgcn_mfma_f32_16x16x32_f16(a1, bfrag[c], acc1, 0, 0, 0);
    }
    if (node < n) {
        float no = norm_out[node];
        hh[(size_t)node * 8 + kg] = pack_half4(acc0[0] * no, acc0[1] * no, acc0[2] * no, acc0[3] * no);
        hh[(size_t)node * 8 + 4 + kg] = pack_half4(acc1[0] * no, acc1[1] * no, acc1[2] * no, acc1[3] * no);
    }
}

// ---------------- gather aggregation: 8 lanes/node, fp16 half4/lane, 8-edge unroll ----------

__device__ __forceinline__ float4 shfl4_8(float4 v, int sl) {
    float4 r;
    r.x = __shfl(v.x, sl, 8);
    r.y = __shfl(v.y, sl, 8);
    r.z = __shfl(v.z, sl, 8);
    r.w = __shfl(v.w, sl, 8);
    return r;
}

// layer 1: agg + norm_in + b1 + relu, GEMM2 (8-lane shfl), prescale norm_out -> h2h (fp16)
__global__ __launch_bounds__(256) void agg1_kernel(const float2* __restrict__ h1h,
                                                   const int* __restrict__ row_ptr,
                                                   const int* __restrict__ deg_arr,
                                                   const int* __restrict__ col,
                                                   const float* __restrict__ norm_in,
                                                   const float* __restrict__ norm_out,
                                                   const float* __restrict__ b1,
                                                   const float* __restrict__ W2,
                                                   float2* __restrict__ h2h, int n) {
    __shared__ float W2l[F_HID * F_HID];  // row k holds W2[k][0..31]
    for (int i = threadIdx.x; i < F_HID * F_HID; i += 256) W2l[i] = W2[i];
    __syncthreads();
    const float4* W24 = reinterpret_cast<const float4*>(W2l);
    int q = threadIdx.x & 7;                 // lane in 8-lane group
    int node = blockIdx.x * 32 + (threadIdx.x >> 3);
    if (node >= n) return;
    int start = row_ptr[node];
    int deg = deg_arr[node];
    float4 acc = make_float4(0.f, 0.f, 0.f, 0.f);
    int jj = 0;
    for (; jj + 8 <= deg; jj += 8) {
        int c = col[start + jj + q];         // 8 lanes: one coalesced 32B load
#pragma unroll
        for (int m = 0; m < 8; ++m) {
            int s = __shfl(c, m, 8);
            float2 v = h1h[(size_t)s * 8 + q];
            unpack_half4(v, acc);
        }
    }
    int rem = deg - jj;
    if (rem > 0) {
        int c = col[start + jj + (q < rem ? q : 0)];
        for (int m = 0; m < rem; ++m) {
            int s = __shfl(c, m, 8);
            float2 v = h1h[(size_t)s * 8 + q];
            unpack_half4(v, acc);
        }
    }
    float ni = norm_in[node];
    const float4 b14 = reinterpret_cast<const float4*>(b1)[q];
    float4 t;
    t.x = fmaxf(acc.x * ni + b14.x, 0.f);
    t.y = fmaxf(acc.y * ni + b14.y, 0.f);
    t.z = fmaxf(acc.z * ni + b14.z, 0.f);
    t.w = fmaxf(acc.w * ni + b14.w, 0.f);
    // GEMM2: o[f] = sum_k t[k] * W2[k][f]; t distributed 4-per-lane over 8 lanes
    float4 o = make_float4(0.f, 0.f, 0.f, 0.f);
#pragma unroll
    for (int sl = 0; sl < 8; ++sl) {
        float4 tt = shfl4_8(t, sl);
        int kb = sl * 4;
        float4 w0 = W24[(kb + 0) * 8 + q];
        float4 w1 = W24[(kb + 1) * 8 + q];
        float4 w2 = W24[(kb + 2) * 8 + q];
        float4 w3 = W24[(kb + 3) * 8 + q];
        o.x += tt.x * w0.x + tt.y * w1.x + tt.z * w2.x + tt.w * w3.x;
        o.y += tt.x * w0.y + tt.y * w1.y + tt.z * w2.y + tt.w * w3.y;
        o.z += tt.x * w0.z + tt.y * w1.z + tt.z * w2.z + tt.w * w3.z;
        o.w += tt.x * w0.w + tt.y * w1.w + tt.z * w2.w + tt.w * w3.w;
    }
    float no = norm_out[node];
    h2h[(size_t)node * 8 + q] = pack_half4(o.x * no, o.y * no, o.z * no, o.w * no);
}

// layer 2: agg + norm_in + b2 -> out (fp32)
__global__ __launch_bounds__(256) void agg2_kernel(const float2* __restrict__ h2h,
                                                   const int* __restrict__ row_ptr,
                                                   const int* __restrict__ deg_arr,
                                                   const int* __restrict__ col,
                                                   const float* __restrict__ norm_in,
                                                   const float* __restrict__ b2,
                                                   float* __restrict__ out, int n) {
    int q = threadIdx.x & 7;
    int node = blockIdx.x * 32 + (threadIdx.x >> 3);
    if (node >= n) return;
    int start = row_ptr[node];
    int deg = deg_arr[node];
    float4 acc = make_float4(0.f, 0.f, 0.f, 0.f);
    int jj = 0;
    for (; jj + 8 <= deg; jj += 8) {
        int c = col[start + jj + q];
#pragma unroll
        for (int m = 0; m < 8; ++m) {
            int s = __shfl(c, m, 8);
            float2 v = h2h[(size_t)s * 8 + q];
            unpack_half4(v, acc);
        }
    }
    int rem = deg - jj;
    if (rem > 0) {
        int c = col[start + jj + (q < rem ? q : 0)];
        for (int m = 0; m < rem; ++m) {
            int s = __shfl(c, m, 8);
            float2 v = h2h[(size_t)s * 8 + q];
            unpack_half4(v, acc);
        }
    }
    float ni = norm_in[node];
    const float4 b24 = reinterpret_cast<const float4*>(b2)[q];
    float4 o;
    o.x = acc.x * ni + b24.x;
    o.y = acc.y * ni + b24.y;
    o.z = acc.z * ni + b24.z;
    o.w = acc.w * ni + b24.w;
    reinterpret_cast<float4*>(out)[(size_t)node * 8 + q] = o;
}

// ---------------- launch ----------------

static inline size_t align256(size_t x) { return (x + 255) & ~(size_t)255; }

extern "C" void kernel_launch(void* const* d_in, const int* in_sizes, int n_in,
                              void* d_out, int out_size, void* d_ws, size_t ws_size,
                              hipStream_t stream) {
    const float* features = (const float*)d_in[0];
    const float* W1 = (const float*)d_in[1];
    const float* b1 = (const float*)d_in[2];
    const float* W2 = (const float*)d_in[3];
    const float* b2 = (const float*)d_in[4];
    const int* src = (const int*)d_in[5];
    const int* dst = (const int*)d_in[6];
    const int E = in_sizes[5];
    const int n = N_NODES;
    float* out = (float*)d_out;

    char* ws = (char*)d_ws;
    size_t off = 0;
    float* norm_out = (float*)(ws + off); off += align256((size_t)n * 4);
    float* norm_in = (float*)(ws + off);  off += align256((size_t)n * 4);
    int* row_ptr = (int*)(ws + off);      off += align256((size_t)n * 4);
    int* deg_arr = (int*)(ws + off);      off += align256((size_t)n * 4);
    unsigned* startD = (unsigned*)(ws + off); off += align256((NBUCK + 1) * 4);
    unsigned* startS = (unsigned*)(ws + off); off += align256((NBUCK + 1) * 4);
    unsigned* totD = (unsigned*)(ws + off);   off += align256(NBUCK * 4);
    unsigned* totS = (unsigned*)(ws + off);   off += align256(NBUCK * 4);
    int* col = (int*)(ws + off);              off += align256((size_t)E * 4);  // 6.4 MB

    // region X: pairD+valS (live: part_scatter -> sort_norms) then h2h (live: agg1 -> agg2)
    size_t regX = off;
    unsigned* pairD = (unsigned*)(ws + regX);                        // 6.4 MB
    unsigned short* valS = (unsigned short*)(ws + regX + (size_t)E * 4);  // 3.2 MB (u16)
    float2* h2h = (float2*)(ws + regX);                              // 6.4 MB (fp16 packed)
    off += align256((size_t)2 * E * 4);
    // region Y: cntD+cntS (live: part_count -> part_scatter) then h1h (live: gemm1 -> agg1)
    size_t regY = off;
    unsigned* cntD = (unsigned*)(ws + regY);                         // 200 KB
    unsigned* cntS = (unsigned*)(ws + regY + (size_t)NBLK * NBUCK * 4);
    float2* h1h = (float2*)(ws + regY);                              // 6.4 MB (fp16 packed)

    // phase A: partition edges by dst-bucket (pairs) and src-bucket (u16 locals)
    part_count<<<NBLK, PART_THREADS, 0, stream>>>(src, dst, E, cntD, cntS);
    col_scan2<<<2 * NBUCK, NBLK, 0, stream>>>(cntD, cntS, totD, totS);
    total_scan2<<<2, 1024, 0, stream>>>(totD, totS, startD, startS);
    part_scatter<<<NBLK, PART_THREADS, 0, stream>>>(src, dst, E, cntD, cntS, startD, startS,
                                                    pairD, valS);

    // phase B fused: LDS-staged counting sort -> CSR (+ norm_in) | src norms
    sort_norms<<<2 * NBUCK, 512, 0, stream>>>(pairD, startD, valS, startS, col, row_ptr,
                                              deg_arr, norm_in, norm_out, n);

    // layer 1 projection via MFMA (+ norm_out prescale), fp16 output
    gemm1_mfma<<<(n + 63) / 64, 256, 0, stream>>>(features, W1, norm_out, h1h, n);

    // gather aggregation (8 lanes/node, fp16 tables), fused epilogues
    agg1_kernel<<<(n + 31) / 32, 256, 0, stream>>>(h1h, row_ptr, deg_arr, col, norm_in,
                                                   norm_out, b1, W2, h2h, n);
    agg2_kernel<<<(n + 31) / 32, 256, 0, stream>>>(h2h, row_ptr, deg_arr, col, norm_in, b2, out, n);
}